// Round 1
// baseline (1437.706 us; speedup 1.0000x reference)
//
#include <hip/hip_runtime.h>

#define N_NODES 50000
#define N_EDGES 800000
#define D 128

// ---------------------------------------------------------------------------
// Phase 1: scatter-add. 32 threads per edge, each thread handles 4 contiguous
// floats (float4 gather from x, 4 scalar f32 atomics into agg).
// ---------------------------------------------------------------------------
__global__ __launch_bounds__(256) void scatter_kernel(
    const float* __restrict__ x, const int* __restrict__ ei,
    float* __restrict__ agg, float* __restrict__ deg) {
  int gid = blockIdx.x * 256 + threadIdx.x;
  int e = gid >> 5;
  if (e >= N_EDGES) return;
  int part = gid & 31;
  int dst = ei[e];            // row (destination)
  int src = ei[N_EDGES + e];  // col (source)
  const float4* x4 = (const float4*)x;
  float4 v = x4[(size_t)src * 32 + part];
  float* base = agg + (size_t)dst * D + part * 4;
  atomicAdd(base + 0, v.x);
  atomicAdd(base + 1, v.y);
  atomicAdd(base + 2, v.z);
  atomicAdd(base + 3, v.w);
  if (part == 0) atomicAdd(deg + dst, 1.0f);
}

// ---------------------------------------------------------------------------
// W [o][d] -> Wt [d][o] so the GEMM inner loop reads coalesced float4 of o.
// ---------------------------------------------------------------------------
__global__ __launch_bounds__(256) void transpose_w(
    const float* __restrict__ W, float* __restrict__ Wt) {
  int i = blockIdx.x * 256 + threadIdx.x;
  if (i < D * D) {
    int o = i >> 7, d = i & 127;
    Wt[d * D + o] = W[i];
  }
}

// ---------------------------------------------------------------------------
// Phase 2: out = relu((agg/deg) @ W^T + b), computed IN PLACE over d_out.
// Block = 256 threads handles 32 rows. Rows staged (pre-scaled by 1/deg) in
// LDS before any write, so in-place is race-free. Register tile 4 rows x 4
// cols per thread. Wt read as coalesced float4 (L1-resident, 64 KB).
// ---------------------------------------------------------------------------
__global__ __launch_bounds__(256) void gemm_relu_kernel(
    float* __restrict__ io, const float* __restrict__ deg,
    const float* __restrict__ Wt, const float* __restrict__ b) {
  __shared__ float a_lds[32 * 128];
  int tid = threadIdx.x;
  int row0 = blockIdx.x * 32;

  // stage 32 rows, scaled by 1/deg
  const float4* g4 = (const float4*)io + (size_t)row0 * 32;
  #pragma unroll
  for (int k = 0; k < 4; ++k) {
    int f = k * 256 + tid;  // float4 index within tile (0..1023)
    int r = f >> 5;         // row within tile
    int grow = row0 + r;
    float4 v = make_float4(0.f, 0.f, 0.f, 0.f);
    float inv = 1.0f;
    if (grow < N_NODES) {
      v = g4[f];
      inv = 1.0f / fmaxf(deg[grow], 1.0f);
    }
    float* dstp = &a_lds[f * 4];
    dstp[0] = v.x * inv;
    dstp[1] = v.y * inv;
    dstp[2] = v.z * inv;
    dstp[3] = v.w * inv;
  }
  __syncthreads();

  int cq = tid & 31;        // column quad: cols cq*4 .. cq*4+3
  int rb = (tid >> 5) * 4;  // rows rb .. rb+3 within tile
  float acc[4][4] = {};
  const float4* Wt4 = (const float4*)Wt;
  #pragma unroll 4
  for (int d = 0; d < 128; ++d) {
    float4 w = Wt4[d * 32 + cq];  // coalesced across lanes, L1-hit
    #pragma unroll
    for (int i = 0; i < 4; ++i) {
      float a = a_lds[(rb + i) * 128 + d];  // 2 addrs/wave -> broadcast, free
      acc[i][0] += a * w.x;
      acc[i][1] += a * w.y;
      acc[i][2] += a * w.z;
      acc[i][3] += a * w.w;
    }
  }

  float4 bb = ((const float4*)b)[cq];
  float4* out4 = (float4*)io;
  #pragma unroll
  for (int i = 0; i < 4; ++i) {
    int grow = row0 + rb + i;
    if (grow < N_NODES) {
      float4 r;
      r.x = fmaxf(acc[i][0] + bb.x, 0.0f);
      r.y = fmaxf(acc[i][1] + bb.y, 0.0f);
      r.z = fmaxf(acc[i][2] + bb.z, 0.0f);
      r.w = fmaxf(acc[i][3] + bb.w, 0.0f);
      out4[(size_t)grow * 32 + cq] = r;
    }
  }
}

extern "C" void kernel_launch(void* const* d_in, const int* in_sizes, int n_in,
                              void* d_out, int out_size, void* d_ws, size_t ws_size,
                              hipStream_t stream) {
  const float* x = (const float*)d_in[0];
  const int* ei = (const int*)d_in[1];
  const float* W = (const float*)d_in[2];
  const float* b = (const float*)d_in[3];
  float* out = (float*)d_out;

  float* deg = (float*)d_ws;                        // 50000 floats
  float* Wt = (float*)((char*)d_ws + 256 * 1024);   // 128x128 floats

  // agg accumulates directly in d_out (zeroed each call -> deterministic)
  hipMemsetAsync(d_out, 0, (size_t)N_NODES * D * sizeof(float), stream);
  hipMemsetAsync(deg, 0, N_NODES * sizeof(float), stream);

  transpose_w<<<(D * D + 255) / 256, 256, 0, stream>>>(W, Wt);

  // 32 threads/edge -> 800000*32/256 = 100000 blocks exactly
  scatter_kernel<<<(N_EDGES * 32) / 256, 256, 0, stream>>>(x, ei, out, deg);

  gemm_relu_kernel<<<(N_NODES + 31) / 32, 256, 0, stream>>>(out, deg, Wt, b);
}

// Round 2
// 304.989 us; speedup vs baseline: 4.7140x; 4.7140x over previous
//
#include <hip/hip_runtime.h>

#define N_NODES 50000
#define N_EDGES 800000
#define D 128

// ---------------- CSR path workspace layout (bytes) ----------------
#define CNT_OFF 0u          // u32[N_NODES]
#define OFF_OFF 200704u     // u32[N_NODES+1]
#define CUR_OFF 401920u     // u32[N_NODES]
#define CSR_OFF 602112u     // i32[N_EDGES]
#define WT_OFF  3802112u    // f32[D*D]
#define WS_NEEDED (WT_OFF + D * D * 4u)

// ===========================================================================
// CSR build
// ===========================================================================
__global__ __launch_bounds__(256) void count_kernel(
    const int* __restrict__ ei, unsigned* __restrict__ cnt) {
  int e = blockIdx.x * 256 + threadIdx.x;
  if (e < N_EDGES) atomicAdd(&cnt[ei[e]], 1u);
}

// Single-block exclusive scan of cnt[0..N_NODES) -> off, cur; off[N]=total.
__global__ __launch_bounds__(1024) void scan_kernel(
    const unsigned* __restrict__ cnt, unsigned* __restrict__ off,
    unsigned* __restrict__ cur) {
  __shared__ unsigned s[1024];
  const int t = threadIdx.x;
  const int CHUNK = (N_NODES + 1023) / 1024;  // 49
  int beg = t * CHUNK;
  int end = min(beg + CHUNK, N_NODES);
  unsigned sum = 0;
  for (int i = beg; i < end; ++i) sum += cnt[i];
  s[t] = sum;
  __syncthreads();
  for (int o = 1; o < 1024; o <<= 1) {
    unsigned add = (t >= o) ? s[t - o] : 0u;
    __syncthreads();
    s[t] += add;
    __syncthreads();
  }
  unsigned running = (t > 0) ? s[t - 1] : 0u;  // exclusive base
  for (int i = beg; i < end; ++i) {
    off[i] = running;
    cur[i] = running;
    running += cnt[i];
  }
  if (t == 0) off[N_NODES] = s[1023];
}

__global__ __launch_bounds__(256) void fill_kernel(
    const int* __restrict__ ei, unsigned* __restrict__ cur,
    int* __restrict__ csr) {
  int e = blockIdx.x * 256 + threadIdx.x;
  if (e < N_EDGES) {
    int dst = ei[e];
    int src = ei[N_EDGES + e];
    unsigned pos = atomicAdd(&cur[dst], 1u);
    csr[pos] = src;
  }
}

// ===========================================================================
// Aggregate: one wave (64 lanes) per node; lane holds float2 (128 floats/row).
// Gathers x[src] rows coalesced, accumulates in regs, writes agg/deg once.
// ===========================================================================
__global__ __launch_bounds__(256) void aggregate_kernel(
    const float* __restrict__ x, const unsigned* __restrict__ off,
    const int* __restrict__ csr, float* __restrict__ agg) {
  int wave = (blockIdx.x * 256 + threadIdx.x) >> 6;
  int lane = threadIdx.x & 63;
  if (wave >= N_NODES) return;
  unsigned beg = off[wave], end = off[wave + 1];
  const float2* x2 = (const float2*)x;
  float ax = 0.f, ay = 0.f;
  unsigned i = beg;
  // 2-way unroll for load-latency overlap
  for (; i + 2 <= end; i += 2) {
    int s0 = csr[i], s1 = csr[i + 1];
    float2 v0 = x2[(size_t)s0 * 64 + lane];
    float2 v1 = x2[(size_t)s1 * 64 + lane];
    ax += v0.x + v1.x;
    ay += v0.y + v1.y;
  }
  if (i < end) {
    float2 v = x2[(size_t)csr[i] * 64 + lane];
    ax += v.x;
    ay += v.y;
  }
  float inv = 1.0f / fmaxf((float)(end - beg), 1.0f);
  float2 r;
  r.x = ax * inv;
  r.y = ay * inv;
  ((float2*)agg)[(size_t)wave * 64 + lane] = r;
}

// ===========================================================================
// W [o][d] -> Wt [d][o]
// ===========================================================================
__global__ __launch_bounds__(256) void transpose_w(
    const float* __restrict__ W, float* __restrict__ Wt) {
  int i = blockIdx.x * 256 + threadIdx.x;
  if (i < D * D) {
    int o = i >> 7, d = i & 127;
    Wt[d * D + o] = W[i];
  }
}

// ===========================================================================
// out = relu(agg @ W^T + b) in place over d_out. If deg != nullptr, rows are
// additionally scaled by 1/max(deg,1) (fallback path); CSR path pre-scales.
// ===========================================================================
__global__ __launch_bounds__(256) void gemm_relu_kernel(
    float* __restrict__ io, const float* __restrict__ deg,
    const float* __restrict__ Wt, const float* __restrict__ b) {
  __shared__ float a_lds[32 * 128];
  int tid = threadIdx.x;
  int row0 = blockIdx.x * 32;

  const float4* g4 = (const float4*)io + (size_t)row0 * 32;
  #pragma unroll
  for (int k = 0; k < 4; ++k) {
    int f = k * 256 + tid;
    int r = f >> 5;
    int grow = row0 + r;
    float4 v = make_float4(0.f, 0.f, 0.f, 0.f);
    float inv = 1.0f;
    if (grow < N_NODES) {
      v = g4[f];
      if (deg) inv = 1.0f / fmaxf(deg[grow], 1.0f);
    }
    float* dstp = &a_lds[f * 4];
    dstp[0] = v.x * inv;
    dstp[1] = v.y * inv;
    dstp[2] = v.z * inv;
    dstp[3] = v.w * inv;
  }
  __syncthreads();

  int cq = tid & 31;
  int rb = (tid >> 5) * 4;
  float acc[4][4] = {};
  const float4* Wt4 = (const float4*)Wt;
  #pragma unroll 4
  for (int d = 0; d < 128; ++d) {
    float4 w = Wt4[d * 32 + cq];
    #pragma unroll
    for (int i = 0; i < 4; ++i) {
      float a = a_lds[(rb + i) * 128 + d];
      acc[i][0] += a * w.x;
      acc[i][1] += a * w.y;
      acc[i][2] += a * w.z;
      acc[i][3] += a * w.w;
    }
  }

  float4 bb = ((const float4*)b)[cq];
  float4* out4 = (float4*)io;
  #pragma unroll
  for (int i = 0; i < 4; ++i) {
    int grow = row0 + rb + i;
    if (grow < N_NODES) {
      float4 r;
      r.x = fmaxf(acc[i][0] + bb.x, 0.0f);
      r.y = fmaxf(acc[i][1] + bb.y, 0.0f);
      r.z = fmaxf(acc[i][2] + bb.z, 0.0f);
      r.w = fmaxf(acc[i][3] + bb.w, 0.0f);
      out4[(size_t)grow * 32 + cq] = r;
    }
  }
}

// ===========================================================================
// Fallback (small ws): original atomic scatter
// ===========================================================================
__global__ __launch_bounds__(256) void scatter_kernel(
    const float* __restrict__ x, const int* __restrict__ ei,
    float* __restrict__ agg, float* __restrict__ deg) {
  int gid = blockIdx.x * 256 + threadIdx.x;
  int e = gid >> 5;
  if (e >= N_EDGES) return;
  int part = gid & 31;
  int dst = ei[e];
  int src = ei[N_EDGES + e];
  const float4* x4 = (const float4*)x;
  float4 v = x4[(size_t)src * 32 + part];
  float* base = agg + (size_t)dst * D + part * 4;
  atomicAdd(base + 0, v.x);
  atomicAdd(base + 1, v.y);
  atomicAdd(base + 2, v.z);
  atomicAdd(base + 3, v.w);
  if (part == 0) atomicAdd(deg + dst, 1.0f);
}

extern "C" void kernel_launch(void* const* d_in, const int* in_sizes, int n_in,
                              void* d_out, int out_size, void* d_ws, size_t ws_size,
                              hipStream_t stream) {
  const float* x = (const float*)d_in[0];
  const int* ei = (const int*)d_in[1];
  const float* W = (const float*)d_in[2];
  const float* b = (const float*)d_in[3];
  float* out = (float*)d_out;

  if (ws_size >= WS_NEEDED) {
    unsigned* cnt = (unsigned*)((char*)d_ws + CNT_OFF);
    unsigned* off = (unsigned*)((char*)d_ws + OFF_OFF);
    unsigned* cur = (unsigned*)((char*)d_ws + CUR_OFF);
    int* csr = (int*)((char*)d_ws + CSR_OFF);
    float* Wt = (float*)((char*)d_ws + WT_OFF);

    hipMemsetAsync(cnt, 0, N_NODES * sizeof(unsigned), stream);
    transpose_w<<<(D * D + 255) / 256, 256, 0, stream>>>(W, Wt);
    count_kernel<<<(N_EDGES + 255) / 256, 256, 0, stream>>>(ei, cnt);
    scan_kernel<<<1, 1024, 0, stream>>>(cnt, off, cur);
    fill_kernel<<<(N_EDGES + 255) / 256, 256, 0, stream>>>(ei, cur, csr);
    aggregate_kernel<<<(N_NODES * 64 + 255) / 256, 256, 0, stream>>>(
        x, off, csr, out);
    gemm_relu_kernel<<<(N_NODES + 31) / 32, 256, 0, stream>>>(
        out, nullptr, Wt, b);
  } else {
    float* deg = (float*)d_ws;
    float* Wt = (float*)((char*)d_ws + 256 * 1024);
    hipMemsetAsync(d_out, 0, (size_t)N_NODES * D * sizeof(float), stream);
    hipMemsetAsync(deg, 0, N_NODES * sizeof(float), stream);
    transpose_w<<<(D * D + 255) / 256, 256, 0, stream>>>(W, Wt);
    scatter_kernel<<<(N_EDGES * 32) / 256, 256, 0, stream>>>(x, ei, out, deg);
    gemm_relu_kernel<<<(N_NODES + 31) / 32, 256, 0, stream>>>(out, deg, Wt, b);
  }
}

// Round 3
// 193.295 us; speedup vs baseline: 7.4379x; 1.5778x over previous
//
#include <hip/hip_runtime.h>

#define N_NODES 50000
#define N_EDGES 800000
#define D 128

#define SCAN_B 256                       // nodes per scan block
#define SCAN_NBLK ((N_NODES + SCAN_B - 1) / SCAN_B)  // 196

// ---------------- CSR path workspace layout (bytes) ----------------
#define CNT_OFF 0u          // u32[N_NODES]
#define OFF_OFF 200704u     // u32[N_NODES+1]
#define CUR_OFF 401920u     // u32[N_NODES]
#define CSR_OFF 602112u     // i32[N_EDGES]
#define WT_OFF  3802112u    // f32[D*D]
#define PART_OFF (WT_OFF + D * D * 4u)        // u32[256] block partial sums
#define BASE_OFF (PART_OFF + 256u * 4u)       // u32[256] block bases
#define WS_NEEDED (BASE_OFF + 256u * 4u)

// ===========================================================================
// CSR build
// ===========================================================================
__global__ __launch_bounds__(256) void count_kernel(
    const int* __restrict__ ei, unsigned* __restrict__ cnt) {
  int e = blockIdx.x * 256 + threadIdx.x;
  if (e < N_EDGES) atomicAdd(&cnt[ei[e]], 1u);
}

// Phase 1: per-block sums of cnt (256 nodes/block) -> partial[block]
__global__ __launch_bounds__(256) void scan_p1(
    const unsigned* __restrict__ cnt, unsigned* __restrict__ partial) {
  int t = threadIdx.x;
  int g = blockIdx.x * SCAN_B + t;
  unsigned c = (g < N_NODES) ? cnt[g] : 0u;
  #pragma unroll
  for (int o = 32; o > 0; o >>= 1) c += __shfl_down(c, o, 64);
  __shared__ unsigned ws[4];
  if ((t & 63) == 0) ws[t >> 6] = c;
  __syncthreads();
  if (t == 0) partial[blockIdx.x] = ws[0] + ws[1] + ws[2] + ws[3];
}

// Phase 2: one small block scans the partials -> base[block]; off[N]=total
__global__ __launch_bounds__(256) void scan_p2(
    const unsigned* __restrict__ partial, unsigned* __restrict__ base,
    unsigned* __restrict__ off) {
  __shared__ unsigned s[256];
  int t = threadIdx.x;
  unsigned v = (t < SCAN_NBLK) ? partial[t] : 0u;
  s[t] = v;
  __syncthreads();
  #pragma unroll
  for (int o = 1; o < 256; o <<= 1) {
    unsigned a = (t >= o) ? s[t - o] : 0u;
    __syncthreads();
    s[t] += a;
    __syncthreads();
  }
  if (t < SCAN_NBLK) base[t] = s[t] - v;  // exclusive
  if (t == 255) off[N_NODES] = s[255];
}

// Phase 3: block-local exclusive scan + base -> off, cur
__global__ __launch_bounds__(256) void scan_p3(
    const unsigned* __restrict__ cnt, const unsigned* __restrict__ base,
    unsigned* __restrict__ off, unsigned* __restrict__ cur) {
  __shared__ unsigned s[256];
  int t = threadIdx.x;
  int g = blockIdx.x * SCAN_B + t;
  unsigned c = (g < N_NODES) ? cnt[g] : 0u;
  s[t] = c;
  __syncthreads();
  #pragma unroll
  for (int o = 1; o < 256; o <<= 1) {
    unsigned a = (t >= o) ? s[t - o] : 0u;
    __syncthreads();
    s[t] += a;
    __syncthreads();
  }
  if (g < N_NODES) {
    unsigned e = base[blockIdx.x] + s[t] - c;
    off[g] = e;
    cur[g] = e;
  }
}

__global__ __launch_bounds__(256) void fill_kernel(
    const int* __restrict__ ei, unsigned* __restrict__ cur,
    int* __restrict__ csr) {
  int e = blockIdx.x * 256 + threadIdx.x;
  if (e < N_EDGES) {
    int dst = ei[e];
    int src = ei[N_EDGES + e];
    unsigned pos = atomicAdd(&cur[dst], 1u);
    csr[pos] = src;
  }
}

// ===========================================================================
// Aggregate: one wave (64 lanes) per node; lane holds float2 (128 floats/row).
// ===========================================================================
__global__ __launch_bounds__(256) void aggregate_kernel(
    const float* __restrict__ x, const unsigned* __restrict__ off,
    const int* __restrict__ csr, float* __restrict__ agg) {
  int wave = (blockIdx.x * 256 + threadIdx.x) >> 6;
  int lane = threadIdx.x & 63;
  if (wave >= N_NODES) return;
  unsigned beg = off[wave], end = off[wave + 1];
  const float2* x2 = (const float2*)x;
  float ax = 0.f, ay = 0.f;
  unsigned i = beg;
  for (; i + 2 <= end; i += 2) {
    int s0 = csr[i], s1 = csr[i + 1];
    float2 v0 = x2[(size_t)s0 * 64 + lane];
    float2 v1 = x2[(size_t)s1 * 64 + lane];
    ax += v0.x + v1.x;
    ay += v0.y + v1.y;
  }
  if (i < end) {
    float2 v = x2[(size_t)csr[i] * 64 + lane];
    ax += v.x;
    ay += v.y;
  }
  float inv = 1.0f / fmaxf((float)(end - beg), 1.0f);
  float2 r;
  r.x = ax * inv;
  r.y = ay * inv;
  ((float2*)agg)[(size_t)wave * 64 + lane] = r;
}

// ===========================================================================
// W [o][d] -> Wt [d][o]
// ===========================================================================
__global__ __launch_bounds__(256) void transpose_w(
    const float* __restrict__ W, float* __restrict__ Wt) {
  int i = blockIdx.x * 256 + threadIdx.x;
  if (i < D * D) {
    int o = i >> 7, d = i & 127;
    Wt[d * D + o] = W[i];
  }
}

// ===========================================================================
// out = relu(agg @ W^T + b) in place over d_out.
// ===========================================================================
__global__ __launch_bounds__(256) void gemm_relu_kernel(
    float* __restrict__ io, const float* __restrict__ deg,
    const float* __restrict__ Wt, const float* __restrict__ b) {
  __shared__ float a_lds[32 * 128];
  int tid = threadIdx.x;
  int row0 = blockIdx.x * 32;

  const float4* g4 = (const float4*)io + (size_t)row0 * 32;
  #pragma unroll
  for (int k = 0; k < 4; ++k) {
    int f = k * 256 + tid;
    int r = f >> 5;
    int grow = row0 + r;
    float4 v = make_float4(0.f, 0.f, 0.f, 0.f);
    float inv = 1.0f;
    if (grow < N_NODES) {
      v = g4[f];
      if (deg) inv = 1.0f / fmaxf(deg[grow], 1.0f);
    }
    float* dstp = &a_lds[f * 4];
    dstp[0] = v.x * inv;
    dstp[1] = v.y * inv;
    dstp[2] = v.z * inv;
    dstp[3] = v.w * inv;
  }
  __syncthreads();

  int cq = tid & 31;
  int rb = (tid >> 5) * 4;
  float acc[4][4] = {};
  const float4* Wt4 = (const float4*)Wt;
  #pragma unroll 4
  for (int d = 0; d < 128; ++d) {
    float4 w = Wt4[d * 32 + cq];
    #pragma unroll
    for (int i = 0; i < 4; ++i) {
      float a = a_lds[(rb + i) * 128 + d];
      acc[i][0] += a * w.x;
      acc[i][1] += a * w.y;
      acc[i][2] += a * w.z;
      acc[i][3] += a * w.w;
    }
  }

  float4 bb = ((const float4*)b)[cq];
  float4* out4 = (float4*)io;
  #pragma unroll
  for (int i = 0; i < 4; ++i) {
    int grow = row0 + rb + i;
    if (grow < N_NODES) {
      float4 r;
      r.x = fmaxf(acc[i][0] + bb.x, 0.0f);
      r.y = fmaxf(acc[i][1] + bb.y, 0.0f);
      r.z = fmaxf(acc[i][2] + bb.z, 0.0f);
      r.w = fmaxf(acc[i][3] + bb.w, 0.0f);
      out4[(size_t)grow * 32 + cq] = r;
    }
  }
}

// ===========================================================================
// Fallback (small ws): atomic scatter
// ===========================================================================
__global__ __launch_bounds__(256) void scatter_kernel(
    const float* __restrict__ x, const int* __restrict__ ei,
    float* __restrict__ agg, float* __restrict__ deg) {
  int gid = blockIdx.x * 256 + threadIdx.x;
  int e = gid >> 5;
  if (e >= N_EDGES) return;
  int part = gid & 31;
  int dst = ei[e];
  int src = ei[N_EDGES + e];
  const float4* x4 = (const float4*)x;
  float4 v = x4[(size_t)src * 32 + part];
  float* base = agg + (size_t)dst * D + part * 4;
  atomicAdd(base + 0, v.x);
  atomicAdd(base + 1, v.y);
  atomicAdd(base + 2, v.z);
  atomicAdd(base + 3, v.w);
  if (part == 0) atomicAdd(deg + dst, 1.0f);
}

extern "C" void kernel_launch(void* const* d_in, const int* in_sizes, int n_in,
                              void* d_out, int out_size, void* d_ws, size_t ws_size,
                              hipStream_t stream) {
  const float* x = (const float*)d_in[0];
  const int* ei = (const int*)d_in[1];
  const float* W = (const float*)d_in[2];
  const float* b = (const float*)d_in[3];
  float* out = (float*)d_out;

  if (ws_size >= WS_NEEDED) {
    unsigned* cnt = (unsigned*)((char*)d_ws + CNT_OFF);
    unsigned* off = (unsigned*)((char*)d_ws + OFF_OFF);
    unsigned* cur = (unsigned*)((char*)d_ws + CUR_OFF);
    int* csr = (int*)((char*)d_ws + CSR_OFF);
    float* Wt = (float*)((char*)d_ws + WT_OFF);
    unsigned* partial = (unsigned*)((char*)d_ws + PART_OFF);
    unsigned* base = (unsigned*)((char*)d_ws + BASE_OFF);

    hipMemsetAsync(cnt, 0, N_NODES * sizeof(unsigned), stream);
    transpose_w<<<(D * D + 255) / 256, 256, 0, stream>>>(W, Wt);
    count_kernel<<<(N_EDGES + 255) / 256, 256, 0, stream>>>(ei, cnt);
    scan_p1<<<SCAN_NBLK, 256, 0, stream>>>(cnt, partial);
    scan_p2<<<1, 256, 0, stream>>>(partial, base, off);
    scan_p3<<<SCAN_NBLK, 256, 0, stream>>>(cnt, base, off, cur);
    fill_kernel<<<(N_EDGES + 255) / 256, 256, 0, stream>>>(ei, cur, csr);
    aggregate_kernel<<<(N_NODES * 64 + 255) / 256, 256, 0, stream>>>(
        x, off, csr, out);
    gemm_relu_kernel<<<(N_NODES + 31) / 32, 256, 0, stream>>>(
        out, nullptr, Wt, b);
  } else {
    float* deg = (float*)d_ws;
    float* Wt = (float*)((char*)d_ws + 256 * 1024);
    hipMemsetAsync(d_out, 0, (size_t)N_NODES * D * sizeof(float), stream);
    hipMemsetAsync(deg, 0, N_NODES * sizeof(float), stream);
    transpose_w<<<(D * D + 255) / 256, 256, 0, stream>>>(W, Wt);
    scatter_kernel<<<(N_EDGES * 32) / 256, 256, 0, stream>>>(x, ei, out, deg);
    gemm_relu_kernel<<<(N_NODES + 31) / 32, 256, 0, stream>>>(out, deg, Wt, b);
  }
}

// Round 4
// 176.421 us; speedup vs baseline: 8.1493x; 1.0956x over previous
//
#include <hip/hip_runtime.h>

#define N_NODES 50000
#define N_EDGES 800000
#define D 128

#define SCAN_B 256
#define SCAN_NBLK ((N_NODES + SCAN_B - 1) / SCAN_B)  // 196

// ---------------- workspace layout (bytes) ----------------
#define CNT_OFF 0u           // u32[N_NODES]
#define OFF_OFF 200704u      // u32[N_NODES+1]
#define CUR_OFF 401920u      // u32[N_NODES]
#define CSR_OFF 602112u      // i32[N_EDGES]
#define WT_OFF  3802112u     // f32[D*D]
#define PART_OFF 3867648u    // u32[256]
#define BASE_OFF 3868672u    // u32[256]
#define XB_OFF   3869696u    // bf16[N_NODES*D] = 12.8 MB
#define AGGB_OFF 16669696u   // bf16[N_NODES*D] = 12.8 MB
#define WS_NEED_A (AGGB_OFF + (unsigned)N_NODES * D * 2u)  // ~29.5 MB
#define WS_NEED_B (BASE_OFF + 1024u)                        // ~3.87 MB

// round-to-nearest-even f32->bf16 pack (a -> low16, b -> high16)
static __device__ __forceinline__ unsigned pack_bf16(float a, float b) {
  unsigned ua = __float_as_uint(a), ub = __float_as_uint(b);
  ua = (ua + 0x7fffu + ((ua >> 16) & 1u)) >> 16;
  ub = (ub + 0x7fffu + ((ub >> 16) & 1u)) & 0xffff0000u;
  return ub | ua;
}
static __device__ __forceinline__ float bf_lo(unsigned v) {
  return __uint_as_float(v << 16);
}
static __device__ __forceinline__ float bf_hi(unsigned v) {
  return __uint_as_float(v & 0xffff0000u);
}

// ===========================================================================
// x f32 -> bf16 (packed), vectorized
// ===========================================================================
__global__ __launch_bounds__(256) void convert_x(
    const float4* __restrict__ x4, uint2* __restrict__ xb) {
  int i = blockIdx.x * 256 + threadIdx.x;
  if (i < N_NODES * D / 4) {
    float4 v = x4[i];
    uint2 r;
    r.x = pack_bf16(v.x, v.y);
    r.y = pack_bf16(v.z, v.w);
    xb[i] = r;
  }
}

// ===========================================================================
// CSR build
// ===========================================================================
__global__ __launch_bounds__(256) void count_kernel(
    const int* __restrict__ ei, unsigned* __restrict__ cnt) {
  int e = blockIdx.x * 256 + threadIdx.x;
  if (e < N_EDGES) atomicAdd(&cnt[ei[e]], 1u);
}

__global__ __launch_bounds__(256) void scan_p1(
    const unsigned* __restrict__ cnt, unsigned* __restrict__ partial) {
  int t = threadIdx.x;
  int g = blockIdx.x * SCAN_B + t;
  unsigned c = (g < N_NODES) ? cnt[g] : 0u;
  #pragma unroll
  for (int o = 32; o > 0; o >>= 1) c += __shfl_down(c, o, 64);
  __shared__ unsigned ws[4];
  if ((t & 63) == 0) ws[t >> 6] = c;
  __syncthreads();
  if (t == 0) partial[blockIdx.x] = ws[0] + ws[1] + ws[2] + ws[3];
}

__global__ __launch_bounds__(256) void scan_p2(
    const unsigned* __restrict__ partial, unsigned* __restrict__ base,
    unsigned* __restrict__ off) {
  __shared__ unsigned s[256];
  int t = threadIdx.x;
  unsigned v = (t < SCAN_NBLK) ? partial[t] : 0u;
  s[t] = v;
  __syncthreads();
  #pragma unroll
  for (int o = 1; o < 256; o <<= 1) {
    unsigned a = (t >= o) ? s[t - o] : 0u;
    __syncthreads();
    s[t] += a;
    __syncthreads();
  }
  if (t < SCAN_NBLK) base[t] = s[t] - v;
  if (t == 255) off[N_NODES] = s[255];
}

__global__ __launch_bounds__(256) void scan_p3(
    const unsigned* __restrict__ cnt, const unsigned* __restrict__ base,
    unsigned* __restrict__ off, unsigned* __restrict__ cur) {
  __shared__ unsigned s[256];
  int t = threadIdx.x;
  int g = blockIdx.x * SCAN_B + t;
  unsigned c = (g < N_NODES) ? cnt[g] : 0u;
  s[t] = c;
  __syncthreads();
  #pragma unroll
  for (int o = 1; o < 256; o <<= 1) {
    unsigned a = (t >= o) ? s[t - o] : 0u;
    __syncthreads();
    s[t] += a;
    __syncthreads();
  }
  if (g < N_NODES) {
    unsigned e = base[blockIdx.x] + s[t] - c;
    off[g] = e;
    cur[g] = e;
  }
}

__global__ __launch_bounds__(256) void fill_kernel(
    const int* __restrict__ ei, unsigned* __restrict__ cur,
    int* __restrict__ csr) {
  int e = blockIdx.x * 256 + threadIdx.x;
  if (e < N_EDGES) {
    int dst = ei[e];
    int src = ei[N_EDGES + e];
    unsigned pos = atomicAdd(&cur[dst], 1u);
    csr[pos] = src;
  }
}

// ===========================================================================
// Aggregate (bf16 gather): one wave per node, lane holds 2 features as f32.
// Gathers 256 B/edge coalesced from xb; writes pre-scaled bf16 agg row once.
// ===========================================================================
__global__ __launch_bounds__(256) void aggregate_bf16(
    const unsigned* __restrict__ xb, const unsigned* __restrict__ off,
    const int* __restrict__ csr, unsigned* __restrict__ aggb) {
  int node = (blockIdx.x * 256 + threadIdx.x) >> 6;
  int lane = threadIdx.x & 63;
  if (node >= N_NODES) return;
  unsigned beg = off[node], end = off[node + 1];
  float ax = 0.f, ay = 0.f;
  unsigned i = beg;
  for (; i + 4 <= end; i += 4) {  // 4-deep for load-latency overlap
    int s0 = csr[i], s1 = csr[i + 1], s2 = csr[i + 2], s3 = csr[i + 3];
    unsigned v0 = xb[(size_t)s0 * 64 + lane];
    unsigned v1 = xb[(size_t)s1 * 64 + lane];
    unsigned v2 = xb[(size_t)s2 * 64 + lane];
    unsigned v3 = xb[(size_t)s3 * 64 + lane];
    ax += bf_lo(v0) + bf_lo(v1) + bf_lo(v2) + bf_lo(v3);
    ay += bf_hi(v0) + bf_hi(v1) + bf_hi(v2) + bf_hi(v3);
  }
  for (; i < end; ++i) {
    unsigned v = xb[(size_t)csr[i] * 64 + lane];
    ax += bf_lo(v);
    ay += bf_hi(v);
  }
  float inv = 1.0f / fmaxf((float)(end - beg), 1.0f);
  aggb[(size_t)node * 64 + lane] = pack_bf16(ax * inv, ay * inv);
}

// ===========================================================================
// W [o][d] -> Wt [d][o] (f32)
// ===========================================================================
__global__ __launch_bounds__(256) void transpose_w(
    const float* __restrict__ W, float* __restrict__ Wt) {
  int i = blockIdx.x * 256 + threadIdx.x;
  if (i < D * D) {
    int o = i >> 7, d = i & 127;
    Wt[d * D + o] = W[i];
  }
}

// ===========================================================================
// out = relu(aggb @ W^T + b), A in bf16 (converted to f32 in LDS), out f32.
// ===========================================================================
__global__ __launch_bounds__(256) void gemm_relu_bf16a(
    const ushort4* __restrict__ aggb, float* __restrict__ out,
    const float* __restrict__ Wt, const float* __restrict__ b) {
  __shared__ float a_lds[32 * 128];
  int tid = threadIdx.x;
  int row0 = blockIdx.x * 32;

  const ushort4* g = aggb + (size_t)row0 * 32;  // 32 ushort4 per row
  #pragma unroll
  for (int k = 0; k < 4; ++k) {
    int f = k * 256 + tid;  // 0..1023
    int r = f >> 5;
    float4 v = make_float4(0.f, 0.f, 0.f, 0.f);
    if (row0 + r < N_NODES) {
      ushort4 u = g[f];
      v.x = __uint_as_float((unsigned)u.x << 16);
      v.y = __uint_as_float((unsigned)u.y << 16);
      v.z = __uint_as_float((unsigned)u.z << 16);
      v.w = __uint_as_float((unsigned)u.w << 16);
    }
    float* dstp = &a_lds[f * 4];
    dstp[0] = v.x;
    dstp[1] = v.y;
    dstp[2] = v.z;
    dstp[3] = v.w;
  }
  __syncthreads();

  int cq = tid & 31;
  int rb = (tid >> 5) * 4;
  float acc[4][4] = {};
  const float4* Wt4 = (const float4*)Wt;
  #pragma unroll 4
  for (int d = 0; d < 128; ++d) {
    float4 w = Wt4[d * 32 + cq];
    #pragma unroll
    for (int i = 0; i < 4; ++i) {
      float a = a_lds[(rb + i) * 128 + d];
      acc[i][0] += a * w.x;
      acc[i][1] += a * w.y;
      acc[i][2] += a * w.z;
      acc[i][3] += a * w.w;
    }
  }

  float4 bb = ((const float4*)b)[cq];
  float4* out4 = (float4*)out;
  #pragma unroll
  for (int i = 0; i < 4; ++i) {
    int grow = row0 + rb + i;
    if (grow < N_NODES) {
      float4 r;
      r.x = fmaxf(acc[i][0] + bb.x, 0.0f);
      r.y = fmaxf(acc[i][1] + bb.y, 0.0f);
      r.z = fmaxf(acc[i][2] + bb.z, 0.0f);
      r.w = fmaxf(acc[i][3] + bb.w, 0.0f);
      out4[(size_t)grow * 32 + cq] = r;
    }
  }
}

// ===========================================================================
// Tier-B kernels (f32 CSR path, in-place over d_out) — R3 fallback
// ===========================================================================
__global__ __launch_bounds__(256) void aggregate_kernel(
    const float* __restrict__ x, const unsigned* __restrict__ off,
    const int* __restrict__ csr, float* __restrict__ agg) {
  int wave = (blockIdx.x * 256 + threadIdx.x) >> 6;
  int lane = threadIdx.x & 63;
  if (wave >= N_NODES) return;
  unsigned beg = off[wave], end = off[wave + 1];
  const float2* x2 = (const float2*)x;
  float ax = 0.f, ay = 0.f;
  unsigned i = beg;
  for (; i + 2 <= end; i += 2) {
    int s0 = csr[i], s1 = csr[i + 1];
    float2 v0 = x2[(size_t)s0 * 64 + lane];
    float2 v1 = x2[(size_t)s1 * 64 + lane];
    ax += v0.x + v1.x;
    ay += v0.y + v1.y;
  }
  if (i < end) {
    float2 v = x2[(size_t)csr[i] * 64 + lane];
    ax += v.x;
    ay += v.y;
  }
  float inv = 1.0f / fmaxf((float)(end - beg), 1.0f);
  float2 r;
  r.x = ax * inv;
  r.y = ay * inv;
  ((float2*)agg)[(size_t)wave * 64 + lane] = r;
}

__global__ __launch_bounds__(256) void gemm_relu_kernel(
    float* __restrict__ io, const float* __restrict__ deg,
    const float* __restrict__ Wt, const float* __restrict__ b) {
  __shared__ float a_lds[32 * 128];
  int tid = threadIdx.x;
  int row0 = blockIdx.x * 32;
  const float4* g4 = (const float4*)io + (size_t)row0 * 32;
  #pragma unroll
  for (int k = 0; k < 4; ++k) {
    int f = k * 256 + tid;
    int r = f >> 5;
    int grow = row0 + r;
    float4 v = make_float4(0.f, 0.f, 0.f, 0.f);
    float inv = 1.0f;
    if (grow < N_NODES) {
      v = g4[f];
      if (deg) inv = 1.0f / fmaxf(deg[grow], 1.0f);
    }
    float* dstp = &a_lds[f * 4];
    dstp[0] = v.x * inv;
    dstp[1] = v.y * inv;
    dstp[2] = v.z * inv;
    dstp[3] = v.w * inv;
  }
  __syncthreads();
  int cq = tid & 31;
  int rb = (tid >> 5) * 4;
  float acc[4][4] = {};
  const float4* Wt4 = (const float4*)Wt;
  #pragma unroll 4
  for (int d = 0; d < 128; ++d) {
    float4 w = Wt4[d * 32 + cq];
    #pragma unroll
    for (int i = 0; i < 4; ++i) {
      float a = a_lds[(rb + i) * 128 + d];
      acc[i][0] += a * w.x;
      acc[i][1] += a * w.y;
      acc[i][2] += a * w.z;
      acc[i][3] += a * w.w;
    }
  }
  float4 bb = ((const float4*)b)[cq];
  float4* out4 = (float4*)io;
  #pragma unroll
  for (int i = 0; i < 4; ++i) {
    int grow = row0 + rb + i;
    if (grow < N_NODES) {
      float4 r;
      r.x = fmaxf(acc[i][0] + bb.x, 0.0f);
      r.y = fmaxf(acc[i][1] + bb.y, 0.0f);
      r.z = fmaxf(acc[i][2] + bb.z, 0.0f);
      r.w = fmaxf(acc[i][3] + bb.w, 0.0f);
      out4[(size_t)grow * 32 + cq] = r;
    }
  }
}

__global__ __launch_bounds__(256) void scatter_kernel(
    const float* __restrict__ x, const int* __restrict__ ei,
    float* __restrict__ agg, float* __restrict__ deg) {
  int gid = blockIdx.x * 256 + threadIdx.x;
  int e = gid >> 5;
  if (e >= N_EDGES) return;
  int part = gid & 31;
  int dst = ei[e];
  int src = ei[N_EDGES + e];
  const float4* x4 = (const float4*)x;
  float4 v = x4[(size_t)src * 32 + part];
  float* base = agg + (size_t)dst * D + part * 4;
  atomicAdd(base + 0, v.x);
  atomicAdd(base + 1, v.y);
  atomicAdd(base + 2, v.z);
  atomicAdd(base + 3, v.w);
  if (part == 0) atomicAdd(deg + dst, 1.0f);
}

extern "C" void kernel_launch(void* const* d_in, const int* in_sizes, int n_in,
                              void* d_out, int out_size, void* d_ws, size_t ws_size,
                              hipStream_t stream) {
  const float* x = (const float*)d_in[0];
  const int* ei = (const int*)d_in[1];
  const float* W = (const float*)d_in[2];
  const float* b = (const float*)d_in[3];
  float* out = (float*)d_out;

  if (ws_size >= WS_NEED_A) {
    unsigned* cnt = (unsigned*)((char*)d_ws + CNT_OFF);
    unsigned* off = (unsigned*)((char*)d_ws + OFF_OFF);
    unsigned* cur = (unsigned*)((char*)d_ws + CUR_OFF);
    int* csr = (int*)((char*)d_ws + CSR_OFF);
    float* Wt = (float*)((char*)d_ws + WT_OFF);
    unsigned* partial = (unsigned*)((char*)d_ws + PART_OFF);
    unsigned* base = (unsigned*)((char*)d_ws + BASE_OFF);
    unsigned* xb = (unsigned*)((char*)d_ws + XB_OFF);
    unsigned* aggb = (unsigned*)((char*)d_ws + AGGB_OFF);

    hipMemsetAsync(cnt, 0, N_NODES * sizeof(unsigned), stream);
    convert_x<<<(N_NODES * D / 4 + 255) / 256, 256, 0, stream>>>(
        (const float4*)x, (uint2*)xb);
    transpose_w<<<(D * D + 255) / 256, 256, 0, stream>>>(W, Wt);
    count_kernel<<<(N_EDGES + 255) / 256, 256, 0, stream>>>(ei, cnt);
    scan_p1<<<SCAN_NBLK, 256, 0, stream>>>(cnt, partial);
    scan_p2<<<1, 256, 0, stream>>>(partial, base, off);
    scan_p3<<<SCAN_NBLK, 256, 0, stream>>>(cnt, base, off, cur);
    fill_kernel<<<(N_EDGES + 255) / 256, 256, 0, stream>>>(ei, cur, csr);
    aggregate_bf16<<<(N_NODES * 64 + 255) / 256, 256, 0, stream>>>(
        xb, off, csr, aggb);
    gemm_relu_bf16a<<<(N_NODES + 31) / 32, 256, 0, stream>>>(
        (const ushort4*)aggb, out, Wt, b);
  } else if (ws_size >= WS_NEED_B) {
    unsigned* cnt = (unsigned*)((char*)d_ws + CNT_OFF);
    unsigned* off = (unsigned*)((char*)d_ws + OFF_OFF);
    unsigned* cur = (unsigned*)((char*)d_ws + CUR_OFF);
    int* csr = (int*)((char*)d_ws + CSR_OFF);
    float* Wt = (float*)((char*)d_ws + WT_OFF);
    unsigned* partial = (unsigned*)((char*)d_ws + PART_OFF);
    unsigned* base = (unsigned*)((char*)d_ws + BASE_OFF);

    hipMemsetAsync(cnt, 0, N_NODES * sizeof(unsigned), stream);
    transpose_w<<<(D * D + 255) / 256, 256, 0, stream>>>(W, Wt);
    count_kernel<<<(N_EDGES + 255) / 256, 256, 0, stream>>>(ei, cnt);
    scan_p1<<<SCAN_NBLK, 256, 0, stream>>>(cnt, partial);
    scan_p2<<<1, 256, 0, stream>>>(partial, base, off);
    scan_p3<<<SCAN_NBLK, 256, 0, stream>>>(cnt, base, off, cur);
    fill_kernel<<<(N_EDGES + 255) / 256, 256, 0, stream>>>(ei, cur, csr);
    aggregate_kernel<<<(N_NODES * 64 + 255) / 256, 256, 0, stream>>>(
        x, off, csr, out);
    gemm_relu_kernel<<<(N_NODES + 31) / 32, 256, 0, stream>>>(
        out, nullptr, Wt, b);
  } else {
    float* deg = (float*)d_ws;
    float* Wt = (float*)((char*)d_ws + 256 * 1024);
    hipMemsetAsync(d_out, 0, (size_t)N_NODES * D * sizeof(float), stream);
    hipMemsetAsync(deg, 0, N_NODES * sizeof(float), stream);
    transpose_w<<<(D * D + 255) / 256, 256, 0, stream>>>(W, Wt);
    scatter_kernel<<<(N_EDGES * 32) / 256, 256, 0, stream>>>(x, ei, out, deg);
    gemm_relu_kernel<<<(N_NODES + 31) / 32, 256, 0, stream>>>(out, deg, Wt, b);
  }
}

// Round 5
// 142.581 us; speedup vs baseline: 10.0835x; 1.2373x over previous
//
#include <hip/hip_runtime.h>

#define N_NODES 50000
#define N_EDGES 800000
#define D 128

// ---- Tier A: bucketed aggregation ----
#define NBKT 782        // ceil(50000/64) buckets of 64 dst nodes
#define SHARDS 8
#define SCAP 320        // entries per (bucket,shard); mean 128, 17-sigma safe

// workspace layout, tier A (bytes)
#define XB_OFF   0u           // bf16[N_NODES*D]            12.8 MB
#define SCNT_OFF 12800000u    // u32[NBKT*SHARDS]           25 KB
#define BKT_OFF  12825024u    // u32[NBKT*SHARDS*SCAP]      8.0 MB
#define WTA_OFF  20832704u    // f32[D*D]
#define WS_NEED_A (WTA_OFF + D * D * 4u)   // ~20.9 MB

// workspace layout, tier B (old CSR path)
#define CNT_OFF 0u
#define OFF_OFF 200704u
#define CUR_OFF 401920u
#define CSR_OFF 602112u
#define WT_OFF  3802112u
#define PART_OFF 3867648u
#define BASE_OFF 3868672u
#define WS_NEED_B (BASE_OFF + 1024u)

#define SCAN_B 256
#define SCAN_NBLK ((N_NODES + SCAN_B - 1) / SCAN_B)  // 196

// round-to-nearest-even f32->bf16 pack (a -> low16, b -> high16)
static __device__ __forceinline__ unsigned pack_bf16(float a, float b) {
  unsigned ua = __float_as_uint(a), ub = __float_as_uint(b);
  ua = (ua + 0x7fffu + ((ua >> 16) & 1u)) >> 16;
  ub = (ub + 0x7fffu + ((ub >> 16) & 1u)) & 0xffff0000u;
  return ub | ua;
}
static __device__ __forceinline__ float bf_lo(unsigned v) {
  return __uint_as_float(v << 16);
}
static __device__ __forceinline__ float bf_hi(unsigned v) {
  return __uint_as_float(v & 0xffff0000u);
}

// ===========================================================================
// x f32 -> bf16 packed
// ===========================================================================
__global__ __launch_bounds__(256) void convert_x(
    const float4* __restrict__ x4, uint2* __restrict__ xb) {
  int i = blockIdx.x * 256 + threadIdx.x;
  if (i < N_NODES * D / 4) {
    float4 v = x4[i];
    uint2 r;
    r.x = pack_bf16(v.x, v.y);
    r.y = pack_bf16(v.z, v.w);
    xb[i] = r;
  }
}

// ===========================================================================
// W [o][d] -> Wt [d][o]
// ===========================================================================
__global__ __launch_bounds__(256) void transpose_w(
    const float* __restrict__ W, float* __restrict__ Wt) {
  int i = blockIdx.x * 256 + threadIdx.x;
  if (i < D * D) {
    int o = i >> 7, d = i & 127;
    Wt[d * D + o] = W[i];
  }
}

// ===========================================================================
// Tier A phase 1: bin edges into (dst>>6, blockIdx%8) regions.
// shard = blockIdx%8 matches the default block->XCD round-robin, so each
// region's lines are dirtied in a single XCD's L2 (write-amp ~1x, not 16x).
// ===========================================================================
__global__ __launch_bounds__(256) void bucketize(
    const int* __restrict__ ei, unsigned* __restrict__ scnt,
    unsigned* __restrict__ bkt) {
  int shard = blockIdx.x & 7;
  for (int e = blockIdx.x * 256 + threadIdx.x; e < N_EDGES; e += 256 * 256) {
    int dst = ei[e];
    int src = ei[N_EDGES + e];
    unsigned cell = (unsigned)(dst >> 6) * SHARDS + shard;
    unsigned pos = atomicAdd(&scnt[cell], 1u);
    if (pos < SCAP)  // statistically impossible to overflow; guard corruption
      bkt[cell * SCAP + pos] = ((unsigned)src << 6) | (unsigned)(dst & 63);
  }
}

// ===========================================================================
// Tier A phase 2: one block per bucket (64 dst nodes).
// Load entries -> LDS counting sort by dst&63 -> wave-per-node register
// gather from bf16 xb -> write pre-scaled f32 agg row to out.
// ===========================================================================
__global__ __launch_bounds__(256) void bucket_agg(
    const unsigned* __restrict__ xb, const unsigned* __restrict__ scnt,
    const unsigned* __restrict__ bkt, float* __restrict__ out) {
  __shared__ unsigned raw[SHARDS * SCAP];  // 10 KB
  __shared__ unsigned lst[SHARDS * SCAP];  // 10 KB
  __shared__ unsigned cnt[64], off[64], cur[64];
  const int t = threadIdx.x;
  const int bucket = blockIdx.x;

  if (t < 64) cnt[t] = 0;
  // load all shard regions into raw[]
  unsigned T = 0;
  #pragma unroll
  for (int s = 0; s < SHARDS; ++s) {
    unsigned c = scnt[bucket * SHARDS + s];
    c = (c > SCAP) ? SCAP : c;
    const unsigned* srcp = &bkt[(unsigned)(bucket * SHARDS + s) * SCAP];
    for (unsigned i = t; i < c; i += 256) raw[T + i] = srcp[i];
    T += c;
  }
  __syncthreads();
  // count per local node
  for (unsigned i = t; i < T; i += 256) atomicAdd(&cnt[raw[i] & 63u], 1u);
  __syncthreads();
  // exclusive scan of cnt[64] in wave 0
  if (t < 64) {
    unsigned c = cnt[t];
    unsigned x = c;
    #pragma unroll
    for (int o = 1; o < 64; o <<= 1) {
      unsigned n = __shfl_up(x, o, 64);
      if (t >= o) x += n;
    }
    off[t] = x - c;
    cur[t] = x - c;
  }
  __syncthreads();
  // scatter src ids into per-node lists
  for (unsigned i = t; i < T; i += 256) {
    unsigned p = raw[i];
    unsigned pos = atomicAdd(&cur[p & 63u], 1u);
    lst[pos] = p >> 6;
  }
  __syncthreads();
  // aggregate: wave per node, lane holds feats (2l, 2l+1)
  const int wave = t >> 6, lane = t & 63;
  for (int r = wave; r < 64; r += 4) {
    int node = bucket * 64 + r;
    if (node >= N_NODES) break;
    unsigned beg = off[r], c = cnt[r];
    float ax = 0.f, ay = 0.f;
    unsigned j = 0;
    for (; j + 4 <= c; j += 4) {
      unsigned s0 = lst[beg + j], s1 = lst[beg + j + 1];
      unsigned s2 = lst[beg + j + 2], s3 = lst[beg + j + 3];
      unsigned v0 = xb[(size_t)s0 * 64 + lane];
      unsigned v1 = xb[(size_t)s1 * 64 + lane];
      unsigned v2 = xb[(size_t)s2 * 64 + lane];
      unsigned v3 = xb[(size_t)s3 * 64 + lane];
      ax += bf_lo(v0) + bf_lo(v1) + bf_lo(v2) + bf_lo(v3);
      ay += bf_hi(v0) + bf_hi(v1) + bf_hi(v2) + bf_hi(v3);
    }
    for (; j < c; ++j) {
      unsigned v = xb[(size_t)lst[beg + j] * 64 + lane];
      ax += bf_lo(v);
      ay += bf_hi(v);
    }
    float inv = 1.0f / fmaxf((float)c, 1.0f);
    float2 rr;
    rr.x = ax * inv;
    rr.y = ay * inv;
    ((float2*)out)[(size_t)node * 64 + lane] = rr;
  }
}

// ===========================================================================
// out = relu(agg @ W^T + b) in place over d_out (rows pre-scaled).
// ===========================================================================
__global__ __launch_bounds__(256) void gemm_relu_kernel(
    float* __restrict__ io, const float* __restrict__ deg,
    const float* __restrict__ Wt, const float* __restrict__ b) {
  __shared__ float a_lds[32 * 128];
  int tid = threadIdx.x;
  int row0 = blockIdx.x * 32;
  const float4* g4 = (const float4*)io + (size_t)row0 * 32;
  #pragma unroll
  for (int k = 0; k < 4; ++k) {
    int f = k * 256 + tid;
    int r = f >> 5;
    int grow = row0 + r;
    float4 v = make_float4(0.f, 0.f, 0.f, 0.f);
    float inv = 1.0f;
    if (grow < N_NODES) {
      v = g4[f];
      if (deg) inv = 1.0f / fmaxf(deg[grow], 1.0f);
    }
    float* dstp = &a_lds[f * 4];
    dstp[0] = v.x * inv;
    dstp[1] = v.y * inv;
    dstp[2] = v.z * inv;
    dstp[3] = v.w * inv;
  }
  __syncthreads();
  int cq = tid & 31;
  int rb = (tid >> 5) * 4;
  float acc[4][4] = {};
  const float4* Wt4 = (const float4*)Wt;
  #pragma unroll 4
  for (int d = 0; d < 128; ++d) {
    float4 w = Wt4[d * 32 + cq];
    #pragma unroll
    for (int i = 0; i < 4; ++i) {
      float a = a_lds[(rb + i) * 128 + d];
      acc[i][0] += a * w.x;
      acc[i][1] += a * w.y;
      acc[i][2] += a * w.z;
      acc[i][3] += a * w.w;
    }
  }
  float4 bb = ((const float4*)b)[cq];
  float4* out4 = (float4*)io;
  #pragma unroll
  for (int i = 0; i < 4; ++i) {
    int grow = row0 + rb + i;
    if (grow < N_NODES) {
      float4 r;
      r.x = fmaxf(acc[i][0] + bb.x, 0.0f);
      r.y = fmaxf(acc[i][1] + bb.y, 0.0f);
      r.z = fmaxf(acc[i][2] + bb.z, 0.0f);
      r.w = fmaxf(acc[i][3] + bb.w, 0.0f);
      out4[(size_t)grow * 32 + cq] = r;
    }
  }
}

// ===========================================================================
// Tier B: CSR build + f32 aggregate (R3 path)
// ===========================================================================
__global__ __launch_bounds__(256) void count_kernel(
    const int* __restrict__ ei, unsigned* __restrict__ cnt) {
  int e = blockIdx.x * 256 + threadIdx.x;
  if (e < N_EDGES) atomicAdd(&cnt[ei[e]], 1u);
}

__global__ __launch_bounds__(256) void scan_p1(
    const unsigned* __restrict__ cnt, unsigned* __restrict__ partial) {
  int t = threadIdx.x;
  int g = blockIdx.x * SCAN_B + t;
  unsigned c = (g < N_NODES) ? cnt[g] : 0u;
  #pragma unroll
  for (int o = 32; o > 0; o >>= 1) c += __shfl_down(c, o, 64);
  __shared__ unsigned ws[4];
  if ((t & 63) == 0) ws[t >> 6] = c;
  __syncthreads();
  if (t == 0) partial[blockIdx.x] = ws[0] + ws[1] + ws[2] + ws[3];
}

__global__ __launch_bounds__(256) void scan_p2(
    const unsigned* __restrict__ partial, unsigned* __restrict__ base,
    unsigned* __restrict__ off) {
  __shared__ unsigned s[256];
  int t = threadIdx.x;
  unsigned v = (t < SCAN_NBLK) ? partial[t] : 0u;
  s[t] = v;
  __syncthreads();
  #pragma unroll
  for (int o = 1; o < 256; o <<= 1) {
    unsigned a = (t >= o) ? s[t - o] : 0u;
    __syncthreads();
    s[t] += a;
    __syncthreads();
  }
  if (t < SCAN_NBLK) base[t] = s[t] - v;
  if (t == 255) off[N_NODES] = s[255];
}

__global__ __launch_bounds__(256) void scan_p3(
    const unsigned* __restrict__ cnt, const unsigned* __restrict__ base,
    unsigned* __restrict__ off, unsigned* __restrict__ cur) {
  __shared__ unsigned s[256];
  int t = threadIdx.x;
  int g = blockIdx.x * SCAN_B + t;
  unsigned c = (g < N_NODES) ? cnt[g] : 0u;
  s[t] = c;
  __syncthreads();
  #pragma unroll
  for (int o = 1; o < 256; o <<= 1) {
    unsigned a = (t >= o) ? s[t - o] : 0u;
    __syncthreads();
    s[t] += a;
    __syncthreads();
  }
  if (g < N_NODES) {
    unsigned e = base[blockIdx.x] + s[t] - c;
    off[g] = e;
    cur[g] = e;
  }
}

__global__ __launch_bounds__(256) void fill_kernel(
    const int* __restrict__ ei, unsigned* __restrict__ cur,
    int* __restrict__ csr) {
  int e = blockIdx.x * 256 + threadIdx.x;
  if (e < N_EDGES) {
    int dst = ei[e];
    int src = ei[N_EDGES + e];
    unsigned pos = atomicAdd(&cur[dst], 1u);
    csr[pos] = src;
  }
}

__global__ __launch_bounds__(256) void aggregate_kernel(
    const float* __restrict__ x, const unsigned* __restrict__ off,
    const int* __restrict__ csr, float* __restrict__ agg) {
  int wave = (blockIdx.x * 256 + threadIdx.x) >> 6;
  int lane = threadIdx.x & 63;
  if (wave >= N_NODES) return;
  unsigned beg = off[wave], end = off[wave + 1];
  const float2* x2 = (const float2*)x;
  float ax = 0.f, ay = 0.f;
  unsigned i = beg;
  for (; i + 2 <= end; i += 2) {
    int s0 = csr[i], s1 = csr[i + 1];
    float2 v0 = x2[(size_t)s0 * 64 + lane];
    float2 v1 = x2[(size_t)s1 * 64 + lane];
    ax += v0.x + v1.x;
    ay += v0.y + v1.y;
  }
  if (i < end) {
    float2 v = x2[(size_t)csr[i] * 64 + lane];
    ax += v.x;
    ay += v.y;
  }
  float inv = 1.0f / fmaxf((float)(end - beg), 1.0f);
  float2 r;
  r.x = ax * inv;
  r.y = ay * inv;
  ((float2*)agg)[(size_t)wave * 64 + lane] = r;
}

// Tier C: atomic scatter fallback
__global__ __launch_bounds__(256) void scatter_kernel(
    const float* __restrict__ x, const int* __restrict__ ei,
    float* __restrict__ agg, float* __restrict__ deg) {
  int gid = blockIdx.x * 256 + threadIdx.x;
  int e = gid >> 5;
  if (e >= N_EDGES) return;
  int part = gid & 31;
  int dst = ei[e];
  int src = ei[N_EDGES + e];
  const float4* x4 = (const float4*)x;
  float4 v = x4[(size_t)src * 32 + part];
  float* base = agg + (size_t)dst * D + part * 4;
  atomicAdd(base + 0, v.x);
  atomicAdd(base + 1, v.y);
  atomicAdd(base + 2, v.z);
  atomicAdd(base + 3, v.w);
  if (part == 0) atomicAdd(deg + dst, 1.0f);
}

extern "C" void kernel_launch(void* const* d_in, const int* in_sizes, int n_in,
                              void* d_out, int out_size, void* d_ws, size_t ws_size,
                              hipStream_t stream) {
  const float* x = (const float*)d_in[0];
  const int* ei = (const int*)d_in[1];
  const float* W = (const float*)d_in[2];
  const float* b = (const float*)d_in[3];
  float* out = (float*)d_out;

  if (ws_size >= WS_NEED_A) {
    unsigned* xb = (unsigned*)((char*)d_ws + XB_OFF);
    unsigned* scnt = (unsigned*)((char*)d_ws + SCNT_OFF);
    unsigned* bkt = (unsigned*)((char*)d_ws + BKT_OFF);
    float* Wt = (float*)((char*)d_ws + WTA_OFF);

    hipMemsetAsync(scnt, 0, NBKT * SHARDS * sizeof(unsigned), stream);
    convert_x<<<(N_NODES * D / 4 + 255) / 256, 256, 0, stream>>>(
        (const float4*)x, (uint2*)xb);
    transpose_w<<<(D * D + 255) / 256, 256, 0, stream>>>(W, Wt);
    bucketize<<<256, 256, 0, stream>>>(ei, scnt, bkt);
    bucket_agg<<<NBKT, 256, 0, stream>>>(xb, scnt, bkt, out);
    gemm_relu_kernel<<<(N_NODES + 31) / 32, 256, 0, stream>>>(
        out, nullptr, Wt, b);
  } else if (ws_size >= WS_NEED_B) {
    unsigned* cnt = (unsigned*)((char*)d_ws + CNT_OFF);
    unsigned* off = (unsigned*)((char*)d_ws + OFF_OFF);
    unsigned* cur = (unsigned*)((char*)d_ws + CUR_OFF);
    int* csr = (int*)((char*)d_ws + CSR_OFF);
    float* Wt = (float*)((char*)d_ws + WT_OFF);
    unsigned* partial = (unsigned*)((char*)d_ws + PART_OFF);
    unsigned* base = (unsigned*)((char*)d_ws + BASE_OFF);

    hipMemsetAsync(cnt, 0, N_NODES * sizeof(unsigned), stream);
    transpose_w<<<(D * D + 255) / 256, 256, 0, stream>>>(W, Wt);
    count_kernel<<<(N_EDGES + 255) / 256, 256, 0, stream>>>(ei, cnt);
    scan_p1<<<SCAN_NBLK, 256, 0, stream>>>(cnt, partial);
    scan_p2<<<1, 256, 0, stream>>>(partial, base, off);
    scan_p3<<<SCAN_NBLK, 256, 0, stream>>>(cnt, base, off, cur);
    fill_kernel<<<(N_EDGES + 255) / 256, 256, 0, stream>>>(ei, cur, csr);
    aggregate_kernel<<<(N_NODES * 64 + 255) / 256, 256, 0, stream>>>(
        x, off, csr, out);
    gemm_relu_kernel<<<(N_NODES + 31) / 32, 256, 0, stream>>>(
        out, nullptr, Wt, b);
  } else {
    float* deg = (float*)d_ws;
    float* Wt = (float*)((char*)d_ws + 256 * 1024);
    hipMemsetAsync(d_out, 0, (size_t)N_NODES * D * sizeof(float), stream);
    hipMemsetAsync(deg, 0, N_NODES * sizeof(float), stream);
    transpose_w<<<(D * D + 255) / 256, 256, 0, stream>>>(W, Wt);
    scatter_kernel<<<(N_EDGES * 32) / 256, 256, 0, stream>>>(x, ei, out, deg);
    gemm_relu_kernel<<<(N_NODES + 31) / 32, 256, 0, stream>>>(out, deg, Wt, b);
  }
}

// Round 6
// 120.020 us; speedup vs baseline: 11.9789x; 1.1880x over previous
//
#include <hip/hip_runtime.h>

#define N_NODES 50000
#define N_EDGES 800000
#define D 128

// ---- Tier A: 32-node buckets + bf16 gather + MFMA gemm ----
#define NBKT 1563       // ceil(50000/32)
#define SHARDS 8
#define SCAP 160        // per (bucket,shard); mean 64, sigma 8 -> 12 sigma

// workspace layout, tier A (bytes)
#define XB_OFF   0u           // bf16[N_NODES*D]          12.8 MB
#define WB_OFF   12800000u    // bf16[D*D]                32 KB
#define SCNT_OFF 12832768u    // u32[NBKT*SHARDS]         50 KB
#define BKT_OFF  12882784u    // u32[NBKT*SHARDS*SCAP]    8.0 MB
#define WS_NEED_A (BKT_OFF + (unsigned)NBKT * SHARDS * SCAP * 4u)  // 20,885,344

// workspace layout, tier B (CSR path)
#define CNT_OFF 0u
#define OFF_OFF 200704u
#define CUR_OFF 401920u
#define CSR_OFF 602112u
#define WT_OFF  3802112u
#define PART_OFF 3867648u
#define BASE_OFF 3868672u
#define WS_NEED_B (BASE_OFF + 1024u)

#define SCAN_B 256
#define SCAN_NBLK ((N_NODES + SCAN_B - 1) / SCAN_B)  // 196

using bf16x8 = __attribute__((ext_vector_type(8))) short;
using f32x4 = __attribute__((ext_vector_type(4))) float;

// round-to-nearest-even f32->bf16
static __device__ __forceinline__ unsigned short bf16_rne(float f) {
  unsigned u = __float_as_uint(f);
  return (unsigned short)((u + 0x7fffu + ((u >> 16) & 1u)) >> 16);
}
static __device__ __forceinline__ unsigned pack_bf16(float a, float b) {
  return (unsigned)bf16_rne(a) | ((unsigned)bf16_rne(b) << 16);
}
static __device__ __forceinline__ float bf_lo(unsigned v) {
  return __uint_as_float(v << 16);
}
static __device__ __forceinline__ float bf_hi(unsigned v) {
  return __uint_as_float(v & 0xffff0000u);
}

// ===========================================================================
// Prep: x f32->bf16 and W f32->bf16 (row-major, [o][d]) in one kernel.
// ===========================================================================
#define XN (N_NODES * D / 4)   // 1,600,000 float4 items
#define WN (D * D / 4)         // 4,096 float4 items
__global__ __launch_bounds__(256) void prep_convert(
    const float4* __restrict__ x4, uint2* __restrict__ xb,
    const float4* __restrict__ w4, uint2* __restrict__ wb) {
  int i = blockIdx.x * 256 + threadIdx.x;
  if (i < XN) {
    float4 v = x4[i];
    uint2 r;
    r.x = pack_bf16(v.x, v.y);
    r.y = pack_bf16(v.z, v.w);
    xb[i] = r;
  } else if (i < XN + WN) {
    int j = i - XN;
    float4 v = w4[j];
    uint2 r;
    r.x = pack_bf16(v.x, v.y);
    r.y = pack_bf16(v.z, v.w);
    wb[j] = r;
  }
}

// ===========================================================================
// Tier A phase 1: bin edges into (dst>>5, blockIdx%8) shard regions.
// shard = blockIdx%8 aligns appends with the block->XCD round-robin.
// ===========================================================================
__global__ __launch_bounds__(256) void bucketize(
    const int* __restrict__ ei, unsigned* __restrict__ scnt,
    unsigned* __restrict__ bkt) {
  int shard = blockIdx.x & 7;
  for (int e = blockIdx.x * 256 + threadIdx.x; e < N_EDGES; e += 256 * 256) {
    int dst = ei[e];
    int src = ei[N_EDGES + e];
    unsigned cell = (unsigned)(dst >> 5) * SHARDS + shard;
    unsigned pos = atomicAdd(&scnt[cell], 1u);
    if (pos < SCAP)  // 12-sigma headroom; guard corruption only
      bkt[cell * SCAP + pos] = ((unsigned)src << 5) | (unsigned)(dst & 31);
  }
}

// ===========================================================================
// Tier A phase 2: one block per 32-node bucket. LDS counting sort by dst&31,
// then wave-per-node register gather from bf16 xb; write pre-scaled f32 row.
// LDS ~10.6 KB -> 8 blocks/CU (thread-limited), vs 25% occupancy at R5.
// ===========================================================================
__global__ __launch_bounds__(256) void bucket_agg32(
    const unsigned* __restrict__ xb, const unsigned* __restrict__ scnt,
    const unsigned* __restrict__ bkt, float* __restrict__ out) {
  __shared__ unsigned raw[SHARDS * SCAP];  // 5120 B
  __shared__ unsigned lst[SHARDS * SCAP];  // 5120 B
  __shared__ unsigned cnt[32], off[32], cur[32];
  const int t = threadIdx.x;
  const int bucket = blockIdx.x;

  if (t < 32) cnt[t] = 0;
  unsigned T = 0;
  #pragma unroll
  for (int s = 0; s < SHARDS; ++s) {
    unsigned c = scnt[bucket * SHARDS + s];
    c = (c > SCAP) ? SCAP : c;
    const unsigned* srcp = &bkt[(unsigned)(bucket * SHARDS + s) * SCAP];
    for (unsigned i = t; i < c; i += 256) raw[T + i] = srcp[i];
    T += c;
  }
  __syncthreads();
  for (unsigned i = t; i < T; i += 256) atomicAdd(&cnt[raw[i] & 31u], 1u);
  __syncthreads();
  if (t < 32) {
    unsigned c = cnt[t];
    unsigned x = c;
    #pragma unroll
    for (int o = 1; o < 32; o <<= 1) {
      unsigned n = __shfl_up(x, o, 64);
      if (t >= o) x += n;
    }
    off[t] = x - c;
    cur[t] = x - c;
  }
  __syncthreads();
  for (unsigned i = t; i < T; i += 256) {
    unsigned p = raw[i];
    unsigned pos = atomicAdd(&cur[p & 31u], 1u);
    lst[pos] = p >> 5;
  }
  __syncthreads();
  const int wave = t >> 6, lane = t & 63;
  for (int r = wave; r < 32; r += 4) {
    int node = bucket * 32 + r;
    if (node >= N_NODES) break;
    unsigned beg = off[r], c = cnt[r];
    float ax = 0.f, ay = 0.f;
    unsigned j = 0;
    for (; j + 4 <= c; j += 4) {
      unsigned s0 = lst[beg + j], s1 = lst[beg + j + 1];
      unsigned s2 = lst[beg + j + 2], s3 = lst[beg + j + 3];
      unsigned v0 = xb[(size_t)s0 * 64 + lane];
      unsigned v1 = xb[(size_t)s1 * 64 + lane];
      unsigned v2 = xb[(size_t)s2 * 64 + lane];
      unsigned v3 = xb[(size_t)s3 * 64 + lane];
      ax += bf_lo(v0) + bf_lo(v1) + bf_lo(v2) + bf_lo(v3);
      ay += bf_hi(v0) + bf_hi(v1) + bf_hi(v2) + bf_hi(v3);
    }
    for (; j < c; ++j) {
      unsigned v = xb[(size_t)lst[beg + j] * 64 + lane];
      ax += bf_lo(v);
      ay += bf_hi(v);
    }
    float inv = 1.0f / fmaxf((float)c, 1.0f);
    float2 rr;
    rr.x = ax * inv;
    rr.y = ay * inv;
    ((float2*)out)[(size_t)node * 64 + lane] = rr;
  }
}

// ===========================================================================
// MFMA gemm: out = relu(agg @ W^T + b), in place over d_out.
// Block = 4 waves = 16 output rows x 128 cols; wave w covers cols [32w,32w+32)
// as two 16x16 C tiles; K=128 via 4 x mfma_f32_16x16x32_bf16 per tile.
// A (f32 agg rows, this block's own 16 rows) converted to bf16 in-register.
// In-place safety: all A reads are consumed by MFMA before __syncthreads;
// stores after. Blocks only touch their own 16 rows.
// A/B use the same (lane>>4,j)->k mapping, so HW K-order is irrelevant.
// C/D: col = lane&15, row = (lane>>4)*4 + reg  [HW-verified mapping].
// ===========================================================================
__global__ __launch_bounds__(256) void gemm_mfma(
    float* __restrict__ io, const unsigned short* __restrict__ wb,
    const float* __restrict__ b) {
  const int wave = threadIdx.x >> 6;
  const int lane = threadIdx.x & 63;
  const int row0 = blockIdx.x * 16;
  const int arow = lane & 15;
  const int khi = lane >> 4;  // 0..3

  // A fragments: lane reads agg[row0+arow][kb*32 + khi*8 .. +8) as f32, cvt.
  const float* ap = io + (size_t)(row0 + arow) * 128 + khi * 8;
  bf16x8 afrag[4];
  #pragma unroll
  for (int kb = 0; kb < 4; ++kb) {
    const float4* p = (const float4*)(ap + kb * 32);
    float4 lo = p[0], hi = p[1];
    afrag[kb][0] = (short)bf16_rne(lo.x);
    afrag[kb][1] = (short)bf16_rne(lo.y);
    afrag[kb][2] = (short)bf16_rne(lo.z);
    afrag[kb][3] = (short)bf16_rne(lo.w);
    afrag[kb][4] = (short)bf16_rne(hi.x);
    afrag[kb][5] = (short)bf16_rne(hi.y);
    afrag[kb][6] = (short)bf16_rne(hi.z);
    afrag[kb][7] = (short)bf16_rne(hi.w);
  }

  f32x4 acc[2];
  acc[0] = (f32x4){0.f, 0.f, 0.f, 0.f};
  acc[1] = (f32x4){0.f, 0.f, 0.f, 0.f};
  #pragma unroll
  for (int ct = 0; ct < 2; ++ct) {
    int o = wave * 32 + ct * 16 + arow;  // B col = W row o
    #pragma unroll
    for (int kb = 0; kb < 4; ++kb) {
      bf16x8 bfrag = *(const bf16x8*)(wb + o * 128 + kb * 32 + khi * 8);
      acc[ct] = __builtin_amdgcn_mfma_f32_16x16x32_bf16(
          afrag[kb], bfrag, acc[ct], 0, 0, 0);
    }
  }
  __syncthreads();  // all waves' A reads complete before any store

  #pragma unroll
  for (int ct = 0; ct < 2; ++ct) {
    int o = wave * 32 + ct * 16 + arow;
    float bias = b[o];
    #pragma unroll
    for (int r = 0; r < 4; ++r) {
      int row = row0 + khi * 4 + r;
      io[(size_t)row * 128 + o] = fmaxf(acc[ct][r] + bias, 0.0f);
    }
  }
}

// ===========================================================================
// Tier B: CSR build + f32 aggregate + vector gemm (R3 path)
// ===========================================================================
__global__ __launch_bounds__(256) void transpose_w(
    const float* __restrict__ W, float* __restrict__ Wt) {
  int i = blockIdx.x * 256 + threadIdx.x;
  if (i < D * D) {
    int o = i >> 7, d = i & 127;
    Wt[d * D + o] = W[i];
  }
}

__global__ __launch_bounds__(256) void count_kernel(
    const int* __restrict__ ei, unsigned* __restrict__ cnt) {
  int e = blockIdx.x * 256 + threadIdx.x;
  if (e < N_EDGES) atomicAdd(&cnt[ei[e]], 1u);
}

__global__ __launch_bounds__(256) void scan_p1(
    const unsigned* __restrict__ cnt, unsigned* __restrict__ partial) {
  int t = threadIdx.x;
  int g = blockIdx.x * SCAN_B + t;
  unsigned c = (g < N_NODES) ? cnt[g] : 0u;
  #pragma unroll
  for (int o = 32; o > 0; o >>= 1) c += __shfl_down(c, o, 64);
  __shared__ unsigned ws[4];
  if ((t & 63) == 0) ws[t >> 6] = c;
  __syncthreads();
  if (t == 0) partial[blockIdx.x] = ws[0] + ws[1] + ws[2] + ws[3];
}

__global__ __launch_bounds__(256) void scan_p2(
    const unsigned* __restrict__ partial, unsigned* __restrict__ base,
    unsigned* __restrict__ off) {
  __shared__ unsigned s[256];
  int t = threadIdx.x;
  unsigned v = (t < SCAN_NBLK) ? partial[t] : 0u;
  s[t] = v;
  __syncthreads();
  #pragma unroll
  for (int o = 1; o < 256; o <<= 1) {
    unsigned a = (t >= o) ? s[t - o] : 0u;
    __syncthreads();
    s[t] += a;
    __syncthreads();
  }
  if (t < SCAN_NBLK) base[t] = s[t] - v;
  if (t == 255) off[N_NODES] = s[255];
}

__global__ __launch_bounds__(256) void scan_p3(
    const unsigned* __restrict__ cnt, const unsigned* __restrict__ base,
    unsigned* __restrict__ off, unsigned* __restrict__ cur) {
  __shared__ unsigned s[256];
  int t = threadIdx.x;
  int g = blockIdx.x * SCAN_B + t;
  unsigned c = (g < N_NODES) ? cnt[g] : 0u;
  s[t] = c;
  __syncthreads();
  #pragma unroll
  for (int o = 1; o < 256; o <<= 1) {
    unsigned a = (t >= o) ? s[t - o] : 0u;
    __syncthreads();
    s[t] += a;
    __syncthreads();
  }
  if (g < N_NODES) {
    unsigned e = base[blockIdx.x] + s[t] - c;
    off[g] = e;
    cur[g] = e;
  }
}

__global__ __launch_bounds__(256) void fill_kernel(
    const int* __restrict__ ei, unsigned* __restrict__ cur,
    int* __restrict__ csr) {
  int e = blockIdx.x * 256 + threadIdx.x;
  if (e < N_EDGES) {
    int dst = ei[e];
    int src = ei[N_EDGES + e];
    unsigned pos = atomicAdd(&cur[dst], 1u);
    csr[pos] = src;
  }
}

__global__ __launch_bounds__(256) void aggregate_kernel(
    const float* __restrict__ x, const unsigned* __restrict__ off,
    const int* __restrict__ csr, float* __restrict__ agg) {
  int wave = (blockIdx.x * 256 + threadIdx.x) >> 6;
  int lane = threadIdx.x & 63;
  if (wave >= N_NODES) return;
  unsigned beg = off[wave], end = off[wave + 1];
  const float2* x2 = (const float2*)x;
  float ax = 0.f, ay = 0.f;
  unsigned i = beg;
  for (; i + 2 <= end; i += 2) {
    int s0 = csr[i], s1 = csr[i + 1];
    float2 v0 = x2[(size_t)s0 * 64 + lane];
    float2 v1 = x2[(size_t)s1 * 64 + lane];
    ax += v0.x + v1.x;
    ay += v0.y + v1.y;
  }
  if (i < end) {
    float2 v = x2[(size_t)csr[i] * 64 + lane];
    ax += v.x;
    ay += v.y;
  }
  float inv = 1.0f / fmaxf((float)(end - beg), 1.0f);
  float2 r;
  r.x = ax * inv;
  r.y = ay * inv;
  ((float2*)agg)[(size_t)wave * 64 + lane] = r;
}

__global__ __launch_bounds__(256) void gemm_relu_kernel(
    float* __restrict__ io, const float* __restrict__ deg,
    const float* __restrict__ Wt, const float* __restrict__ b) {
  __shared__ float a_lds[32 * 128];
  int tid = threadIdx.x;
  int row0 = blockIdx.x * 32;
  const float4* g4 = (const float4*)io + (size_t)row0 * 32;
  #pragma unroll
  for (int k = 0; k < 4; ++k) {
    int f = k * 256 + tid;
    int r = f >> 5;
    int grow = row0 + r;
    float4 v = make_float4(0.f, 0.f, 0.f, 0.f);
    float inv = 1.0f;
    if (grow < N_NODES) {
      v = g4[f];
      if (deg) inv = 1.0f / fmaxf(deg[grow], 1.0f);
    }
    float* dstp = &a_lds[f * 4];
    dstp[0] = v.x * inv;
    dstp[1] = v.y * inv;
    dstp[2] = v.z * inv;
    dstp[3] = v.w * inv;
  }
  __syncthreads();
  int cq = tid & 31;
  int rb = (tid >> 5) * 4;
  float acc[4][4] = {};
  const float4* Wt4 = (const float4*)Wt;
  #pragma unroll 4
  for (int d = 0; d < 128; ++d) {
    float4 w = Wt4[d * 32 + cq];
    #pragma unroll
    for (int i = 0; i < 4; ++i) {
      float a = a_lds[(rb + i) * 128 + d];
      acc[i][0] += a * w.x;
      acc[i][1] += a * w.y;
      acc[i][2] += a * w.z;
      acc[i][3] += a * w.w;
    }
  }
  float4 bb = ((const float4*)b)[cq];
  float4* out4 = (float4*)io;
  #pragma unroll
  for (int i = 0; i < 4; ++i) {
    int grow = row0 + rb + i;
    if (grow < N_NODES) {
      float4 r;
      r.x = fmaxf(acc[i][0] + bb.x, 0.0f);
      r.y = fmaxf(acc[i][1] + bb.y, 0.0f);
      r.z = fmaxf(acc[i][2] + bb.z, 0.0f);
      r.w = fmaxf(acc[i][3] + bb.w, 0.0f);
      out4[(size_t)grow * 32 + cq] = r;
    }
  }
}

__global__ __launch_bounds__(256) void scatter_kernel(
    const float* __restrict__ x, const int* __restrict__ ei,
    float* __restrict__ agg, float* __restrict__ deg) {
  int gid = blockIdx.x * 256 + threadIdx.x;
  int e = gid >> 5;
  if (e >= N_EDGES) return;
  int part = gid & 31;
  int dst = ei[e];
  int src = ei[N_EDGES + e];
  const float4* x4 = (const float4*)x;
  float4 v = x4[(size_t)src * 32 + part];
  float* base = agg + (size_t)dst * D + part * 4;
  atomicAdd(base + 0, v.x);
  atomicAdd(base + 1, v.y);
  atomicAdd(base + 2, v.z);
  atomicAdd(base + 3, v.w);
  if (part == 0) atomicAdd(deg + dst, 1.0f);
}

extern "C" void kernel_launch(void* const* d_in, const int* in_sizes, int n_in,
                              void* d_out, int out_size, void* d_ws, size_t ws_size,
                              hipStream_t stream) {
  const float* x = (const float*)d_in[0];
  const int* ei = (const int*)d_in[1];
  const float* W = (const float*)d_in[2];
  const float* b = (const float*)d_in[3];
  float* out = (float*)d_out;

  if (ws_size >= WS_NEED_A) {
    unsigned* xb = (unsigned*)((char*)d_ws + XB_OFF);
    unsigned short* wb = (unsigned short*)((char*)d_ws + WB_OFF);
    unsigned* scnt = (unsigned*)((char*)d_ws + SCNT_OFF);
    unsigned* bkt = (unsigned*)((char*)d_ws + BKT_OFF);

    hipMemsetAsync(scnt, 0, NBKT * SHARDS * sizeof(unsigned), stream);
    prep_convert<<<(XN + WN + 255) / 256, 256, 0, stream>>>(
        (const float4*)x, (uint2*)xb, (const float4*)W, (uint2*)wb);
    bucketize<<<256, 256, 0, stream>>>(ei, scnt, bkt);
    bucket_agg32<<<NBKT, 256, 0, stream>>>(xb, scnt, bkt, out);
    gemm_mfma<<<N_NODES / 16, 256, 0, stream>>>(out, wb, b);
  } else if (ws_size >= WS_NEED_B) {
    unsigned* cnt = (unsigned*)((char*)d_ws + CNT_OFF);
    unsigned* off = (unsigned*)((char*)d_ws + OFF_OFF);
    unsigned* cur = (unsigned*)((char*)d_ws + CUR_OFF);
    int* csr = (int*)((char*)d_ws + CSR_OFF);
    float* Wt = (float*)((char*)d_ws + WT_OFF);
    unsigned* partial = (unsigned*)((char*)d_ws + PART_OFF);
    unsigned* base = (unsigned*)((char*)d_ws + BASE_OFF);

    hipMemsetAsync(cnt, 0, N_NODES * sizeof(unsigned), stream);
    transpose_w<<<(D * D + 255) / 256, 256, 0, stream>>>(W, Wt);
    count_kernel<<<(N_EDGES + 255) / 256, 256, 0, stream>>>(ei, cnt);
    scan_p1<<<SCAN_NBLK, 256, 0, stream>>>(cnt, partial);
    scan_p2<<<1, 256, 0, stream>>>(partial, base, off);
    scan_p3<<<SCAN_NBLK, 256, 0, stream>>>(cnt, base, off, cur);
    fill_kernel<<<(N_EDGES + 255) / 256, 256, 0, stream>>>(ei, cur, csr);
    aggregate_kernel<<<(N_NODES * 64 + 255) / 256, 256, 0, stream>>>(
        x, off, csr, out);
    gemm_relu_kernel<<<(N_NODES + 31) / 32, 256, 0, stream>>>(
        out, nullptr, Wt, b);
  } else {
    float* deg = (float*)d_ws;
    float* Wt = (float*)((char*)d_ws + 256 * 1024);
    hipMemsetAsync(d_out, 0, (size_t)N_NODES * D * sizeof(float), stream);
    hipMemsetAsync(deg, 0, N_NODES * sizeof(float), stream);
    transpose_w<<<(D * D + 255) / 256, 256, 0, stream>>>(W, Wt);
    scatter_kernel<<<(N_EDGES * 32) / 256, 256, 0, stream>>>(x, ei, out, deg);
    gemm_relu_kernel<<<(N_NODES + 31) / 32, 256, 0, stream>>>(out, deg, Wt, b);
  }
}

// Round 7
// 99.034 us; speedup vs baseline: 14.5173x; 1.2119x over previous
//
#include <hip/hip_runtime.h>

#define N_NODES 50000
#define N_EDGES 800000
#define D 128

// ---- Tier A: fused phase1 (convert+bucketize) + fused agg+MFMA-gemm ----
#define NBKT 1563       // ceil(50000/32) buckets of 32 dst nodes
#define SHARDS 8
#define SCAP 160        // per (bucket,shard); mean 64, sigma 8 -> 12 sigma
#define EBLK 3125       // edge blocks: 3125*256 == N_EDGES exactly
#define XN (N_NODES * D / 4)   // float4 items of x
#define WN (D * D / 4)         // float4 items of W
#define CBLK ((XN + WN + 255) / 256)

// workspace layout, tier A (bytes)
#define XB_OFF   0u           // bf16[N_NODES*D]          12.8 MB
#define WB_OFF   12800000u    // bf16[D*D]                32 KB
#define SCNT_OFF 12832768u    // u32[NBKT*SHARDS]         50 KB
#define BKT_OFF  12882784u    // u32[NBKT*SHARDS*SCAP]    8.0 MB
#define WS_NEED_A (BKT_OFF + (unsigned)NBKT * SHARDS * SCAP * 4u)  // 20,885,344

// workspace layout, tier B (CSR path)
#define CNT_OFF 0u
#define OFF_OFF 200704u
#define CUR_OFF 401920u
#define CSR_OFF 602112u
#define WT_OFF  3802112u
#define PART_OFF 3867648u
#define BASE_OFF 3868672u
#define WS_NEED_B (BASE_OFF + 1024u)

#define SCAN_B 256
#define SCAN_NBLK ((N_NODES + SCAN_B - 1) / SCAN_B)  // 196

using bf16x8 = __attribute__((ext_vector_type(8))) short;
using f32x4 = __attribute__((ext_vector_type(4))) float;

// round-to-nearest-even f32->bf16
static __device__ __forceinline__ unsigned short bf16_rne(float f) {
  unsigned u = __float_as_uint(f);
  return (unsigned short)((u + 0x7fffu + ((u >> 16) & 1u)) >> 16);
}
static __device__ __forceinline__ unsigned pack_bf16(float a, float b) {
  return (unsigned)bf16_rne(a) | ((unsigned)bf16_rne(b) << 16);
}
static __device__ __forceinline__ float bf_lo(unsigned v) {
  return __uint_as_float(v << 16);
}
static __device__ __forceinline__ float bf_hi(unsigned v) {
  return __uint_as_float(v & 0xffff0000u);
}

// ===========================================================================
// phase1: edge blocks [0,EBLK) bin edges (1 edge/thread, full parallelism to
// hide atomic latency); convert blocks [EBLK,EBLK+CBLK) stream x,W f32->bf16.
// The BW-bound convert co-resides with the latency-bound binning.
// ===========================================================================
__global__ __launch_bounds__(256) void phase1(
    const float4* __restrict__ x4, uint2* __restrict__ xb,
    const float4* __restrict__ w4, uint2* __restrict__ wb,
    const int* __restrict__ ei, unsigned* __restrict__ scnt,
    unsigned* __restrict__ bkt) {
  if (blockIdx.x < EBLK) {
    int e = blockIdx.x * 256 + threadIdx.x;  // EBLK*256 == N_EDGES
    int dst = ei[e];
    int src = ei[N_EDGES + e];
    unsigned cell = (unsigned)(dst >> 5) * SHARDS + (blockIdx.x & 7);
    unsigned pos = atomicAdd(&scnt[cell], 1u);
    if (pos < SCAP)  // 12-sigma headroom; guards corruption only
      bkt[cell * SCAP + pos] = ((unsigned)src << 5) | (unsigned)(dst & 31);
  } else {
    int i = (blockIdx.x - EBLK) * 256 + threadIdx.x;
    if (i < XN) {
      float4 v = x4[i];
      uint2 r;
      r.x = pack_bf16(v.x, v.y);
      r.y = pack_bf16(v.z, v.w);
      xb[i] = r;
    } else if (i < XN + WN) {
      int j = i - XN;
      float4 v = w4[j];
      uint2 r;
      r.x = pack_bf16(v.x, v.y);
      r.y = pack_bf16(v.z, v.w);
      wb[j] = r;
    }
  }
}

// ===========================================================================
// agg_gemm: one block per 32-node bucket.
//  A) counting sort (two passes over this bucket's bkt entries, L2-hot) ->
//     per-node src lists (u16) in LDS.
//  B) wave-per-node register gather from bf16 xb; write mean row to LDS as
//     packed bf16, word-swizzled (w ^ ((row&7)<<2)) for conflict-light b128.
//  C) 32x128 @ 128x128 MFMA gemm straight from LDS + bias + relu -> d_out.
// d_out written exactly once; no in-place hazard. LDS ~11 KB -> 8 blocks/CU.
// A/B frags share the (lane>>4)->k mapping so HW K-order cancels.
// C/D: col(lane&15) = B-row = output feature o; row = (lane>>4)*4+reg.
// ===========================================================================
__global__ __launch_bounds__(256) void agg_gemm(
    const unsigned* __restrict__ xb, const unsigned short* __restrict__ wb,
    const unsigned* __restrict__ scnt, const unsigned* __restrict__ bkt,
    const float* __restrict__ b, float* __restrict__ out) {
  __shared__ unsigned short lst[SHARDS * SCAP];  // 2560 B (src ids < 65536)
  __shared__ unsigned abuf[32 * 64];             // 8 KB packed-bf16 rows
  __shared__ unsigned cnt[32], off[32], cur[32];
  const int t = threadIdx.x;
  const int bucket = blockIdx.x;

  if (t < 32) cnt[t] = 0;
  __syncthreads();
  // pass 1: count per local node
  #pragma unroll
  for (int s = 0; s < SHARDS; ++s) {
    unsigned cell = (unsigned)bucket * SHARDS + s;
    unsigned c = scnt[cell];
    c = (c > SCAP) ? SCAP : c;
    const unsigned* p = &bkt[cell * SCAP];
    for (unsigned i = t; i < c; i += 256) atomicAdd(&cnt[p[i] & 31u], 1u);
  }
  __syncthreads();
  if (t < 32) {
    unsigned c = cnt[t], x = c;
    #pragma unroll
    for (int o = 1; o < 32; o <<= 1) {
      unsigned n = __shfl_up(x, o, 64);
      if (t >= o) x += n;
    }
    off[t] = x - c;
    cur[t] = x - c;
  }
  __syncthreads();
  // pass 2: scatter src ids into per-node lists (bkt re-read is L2-hot)
  #pragma unroll
  for (int s = 0; s < SHARDS; ++s) {
    unsigned cell = (unsigned)bucket * SHARDS + s;
    unsigned c = scnt[cell];
    c = (c > SCAP) ? SCAP : c;
    const unsigned* p = &bkt[cell * SCAP];
    for (unsigned i = t; i < c; i += 256) {
      unsigned e = p[i];
      unsigned pos = atomicAdd(&cur[e & 31u], 1u);
      lst[pos] = (unsigned short)(e >> 5);
    }
  }
  __syncthreads();

  // B) aggregate: wave per node; lane holds features (2*lane, 2*lane+1)
  const int wave = t >> 6, lane = t & 63;
  for (int r = wave; r < 32; r += 4) {
    unsigned beg = off[r], c = cnt[r];
    float ax = 0.f, ay = 0.f;
    unsigned j = 0;
    for (; j + 4 <= c; j += 4) {
      unsigned s0 = lst[beg + j], s1 = lst[beg + j + 1];
      unsigned s2 = lst[beg + j + 2], s3 = lst[beg + j + 3];
      unsigned v0 = xb[(size_t)s0 * 64 + lane];
      unsigned v1 = xb[(size_t)s1 * 64 + lane];
      unsigned v2 = xb[(size_t)s2 * 64 + lane];
      unsigned v3 = xb[(size_t)s3 * 64 + lane];
      ax += bf_lo(v0) + bf_lo(v1) + bf_lo(v2) + bf_lo(v3);
      ay += bf_hi(v0) + bf_hi(v1) + bf_hi(v2) + bf_hi(v3);
    }
    for (; j < c; ++j) {
      unsigned v = xb[(size_t)lst[beg + j] * 64 + lane];
      ax += bf_lo(v);
      ay += bf_hi(v);
    }
    float inv = 1.0f / fmaxf((float)c, 1.0f);
    // swizzled write: word l -> l ^ ((r&7)<<2); permutation of low bits,
    // conflict-free (2 lanes/bank), inverse applied on the read side.
    abuf[r * 64 + (lane ^ ((r & 7) << 2))] = pack_bf16(ax * inv, ay * inv);
  }
  __syncthreads();

  // C) MFMA gemm: wave w -> rows [16*(w>>1),+16), cols [(w&1)*64,+64)
  const int rt = wave >> 1;
  const int ch = (wave & 1) * 64;
  const int arow = lane & 15, khi = lane >> 4;
  const int ar = rt * 16 + arow;
  bf16x8 afrag[4];
  #pragma unroll
  for (int kb = 0; kb < 4; ++kb) {
    int w0 = (kb * 16 + khi * 4) ^ ((ar & 7) << 2);  // stays 4-word aligned
    afrag[kb] = *(const bf16x8*)&abuf[ar * 64 + w0];
  }
  #pragma unroll
  for (int ct = 0; ct < 4; ++ct) {
    int o = ch + ct * 16 + arow;  // B row = W row = output feature
    f32x4 acc = (f32x4){0.f, 0.f, 0.f, 0.f};
    #pragma unroll
    for (int kb = 0; kb < 4; ++kb) {
      bf16x8 bfrag = *(const bf16x8*)(wb + o * 128 + kb * 32 + khi * 8);
      acc = __builtin_amdgcn_mfma_f32_16x16x32_bf16(afrag[kb], bfrag, acc,
                                                    0, 0, 0);
    }
    float bias = b[o];
    #pragma unroll
    for (int rg = 0; rg < 4; ++rg) {
      int row = bucket * 32 + rt * 16 + khi * 4 + rg;
      if (row < N_NODES)
        out[(size_t)row * 128 + o] = fmaxf(acc[rg] + bias, 0.0f);
    }
  }
}

// ===========================================================================
// Tier B: CSR build + f32 aggregate + vector gemm (R3 path)
// ===========================================================================
__global__ __launch_bounds__(256) void transpose_w(
    const float* __restrict__ W, float* __restrict__ Wt) {
  int i = blockIdx.x * 256 + threadIdx.x;
  if (i < D * D) {
    int o = i >> 7, d = i & 127;
    Wt[d * D + o] = W[i];
  }
}

__global__ __launch_bounds__(256) void count_kernel(
    const int* __restrict__ ei, unsigned* __restrict__ cnt) {
  int e = blockIdx.x * 256 + threadIdx.x;
  if (e < N_EDGES) atomicAdd(&cnt[ei[e]], 1u);
}

__global__ __launch_bounds__(256) void scan_p1(
    const unsigned* __restrict__ cnt, unsigned* __restrict__ partial) {
  int t = threadIdx.x;
  int g = blockIdx.x * SCAN_B + t;
  unsigned c = (g < N_NODES) ? cnt[g] : 0u;
  #pragma unroll
  for (int o = 32; o > 0; o >>= 1) c += __shfl_down(c, o, 64);
  __shared__ unsigned ws[4];
  if ((t & 63) == 0) ws[t >> 6] = c;
  __syncthreads();
  if (t == 0) partial[blockIdx.x] = ws[0] + ws[1] + ws[2] + ws[3];
}

__global__ __launch_bounds__(256) void scan_p2(
    const unsigned* __restrict__ partial, unsigned* __restrict__ base,
    unsigned* __restrict__ off) {
  __shared__ unsigned s[256];
  int t = threadIdx.x;
  unsigned v = (t < SCAN_NBLK) ? partial[t] : 0u;
  s[t] = v;
  __syncthreads();
  #pragma unroll
  for (int o = 1; o < 256; o <<= 1) {
    unsigned a = (t >= o) ? s[t - o] : 0u;
    __syncthreads();
    s[t] += a;
    __syncthreads();
  }
  if (t < SCAN_NBLK) base[t] = s[t] - v;
  if (t == 255) off[N_NODES] = s[255];
}

__global__ __launch_bounds__(256) void scan_p3(
    const unsigned* __restrict__ cnt, const unsigned* __restrict__ base,
    unsigned* __restrict__ off, unsigned* __restrict__ cur) {
  __shared__ unsigned s[256];
  int t = threadIdx.x;
  int g = blockIdx.x * SCAN_B + t;
  unsigned c = (g < N_NODES) ? cnt[g] : 0u;
  s[t] = c;
  __syncthreads();
  #pragma unroll
  for (int o = 1; o < 256; o <<= 1) {
    unsigned a = (t >= o) ? s[t - o] : 0u;
    __syncthreads();
    s[t] += a;
    __syncthreads();
  }
  if (g < N_NODES) {
    unsigned e = base[blockIdx.x] + s[t] - c;
    off[g] = e;
    cur[g] = e;
  }
}

__global__ __launch_bounds__(256) void fill_kernel(
    const int* __restrict__ ei, unsigned* __restrict__ cur,
    int* __restrict__ csr) {
  int e = blockIdx.x * 256 + threadIdx.x;
  if (e < N_EDGES) {
    int dst = ei[e];
    int src = ei[N_EDGES + e];
    unsigned pos = atomicAdd(&cur[dst], 1u);
    csr[pos] = src;
  }
}

__global__ __launch_bounds__(256) void aggregate_kernel(
    const float* __restrict__ x, const unsigned* __restrict__ off,
    const int* __restrict__ csr, float* __restrict__ agg) {
  int wave = (blockIdx.x * 256 + threadIdx.x) >> 6;
  int lane = threadIdx.x & 63;
  if (wave >= N_NODES) return;
  unsigned beg = off[wave], end = off[wave + 1];
  const float2* x2 = (const float2*)x;
  float ax = 0.f, ay = 0.f;
  unsigned i = beg;
  for (; i + 2 <= end; i += 2) {
    int s0 = csr[i], s1 = csr[i + 1];
    float2 v0 = x2[(size_t)s0 * 64 + lane];
    float2 v1 = x2[(size_t)s1 * 64 + lane];
    ax += v0.x + v1.x;
    ay += v0.y + v1.y;
  }
  if (i < end) {
    float2 v = x2[(size_t)csr[i] * 64 + lane];
    ax += v.x;
    ay += v.y;
  }
  float inv = 1.0f / fmaxf((float)(end - beg), 1.0f);
  float2 r;
  r.x = ax * inv;
  r.y = ay * inv;
  ((float2*)agg)[(size_t)wave * 64 + lane] = r;
}

__global__ __launch_bounds__(256) void gemm_relu_kernel(
    float* __restrict__ io, const float* __restrict__ deg,
    const float* __restrict__ Wt, const float* __restrict__ b) {
  __shared__ float a_lds[32 * 128];
  int tid = threadIdx.x;
  int row0 = blockIdx.x * 32;
  const float4* g4 = (const float4*)io + (size_t)row0 * 32;
  #pragma unroll
  for (int k = 0; k < 4; ++k) {
    int f = k * 256 + tid;
    int r = f >> 5;
    int grow = row0 + r;
    float4 v = make_float4(0.f, 0.f, 0.f, 0.f);
    float inv = 1.0f;
    if (grow < N_NODES) {
      v = g4[f];
      if (deg) inv = 1.0f / fmaxf(deg[grow], 1.0f);
    }
    float* dstp = &a_lds[f * 4];
    dstp[0] = v.x * inv;
    dstp[1] = v.y * inv;
    dstp[2] = v.z * inv;
    dstp[3] = v.w * inv;
  }
  __syncthreads();
  int cq = tid & 31;
  int rb = (tid >> 5) * 4;
  float acc[4][4] = {};
  const float4* Wt4 = (const float4*)Wt;
  #pragma unroll 4
  for (int d = 0; d < 128; ++d) {
    float4 w = Wt4[d * 32 + cq];
    #pragma unroll
    for (int i = 0; i < 4; ++i) {
      float a = a_lds[(rb + i) * 128 + d];
      acc[i][0] += a * w.x;
      acc[i][1] += a * w.y;
      acc[i][2] += a * w.z;
      acc[i][3] += a * w.w;
    }
  }
  float4 bb = ((const float4*)b)[cq];
  float4* out4 = (float4*)io;
  #pragma unroll
  for (int i = 0; i < 4; ++i) {
    int grow = row0 + rb + i;
    if (grow < N_NODES) {
      float4 r;
      r.x = fmaxf(acc[i][0] + bb.x, 0.0f);
      r.y = fmaxf(acc[i][1] + bb.y, 0.0f);
      r.z = fmaxf(acc[i][2] + bb.z, 0.0f);
      r.w = fmaxf(acc[i][3] + bb.w, 0.0f);
      out4[(size_t)grow * 32 + cq] = r;
    }
  }
}

__global__ __launch_bounds__(256) void scatter_kernel(
    const float* __restrict__ x, const int* __restrict__ ei,
    float* __restrict__ agg, float* __restrict__ deg) {
  int gid = blockIdx.x * 256 + threadIdx.x;
  int e = gid >> 5;
  if (e >= N_EDGES) return;
  int part = gid & 31;
  int dst = ei[e];
  int src = ei[N_EDGES + e];
  const float4* x4 = (const float4*)x;
  float4 v = x4[(size_t)src * 32 + part];
  float* base = agg + (size_t)dst * D + part * 4;
  atomicAdd(base + 0, v.x);
  atomicAdd(base + 1, v.y);
  atomicAdd(base + 2, v.z);
  atomicAdd(base + 3, v.w);
  if (part == 0) atomicAdd(deg + dst, 1.0f);
}

extern "C" void kernel_launch(void* const* d_in, const int* in_sizes, int n_in,
                              void* d_out, int out_size, void* d_ws, size_t ws_size,
                              hipStream_t stream) {
  const float* x = (const float*)d_in[0];
  const int* ei = (const int*)d_in[1];
  const float* W = (const float*)d_in[2];
  const float* b = (const float*)d_in[3];
  float* out = (float*)d_out;

  if (ws_size >= WS_NEED_A) {
    unsigned* xb = (unsigned*)((char*)d_ws + XB_OFF);
    unsigned short* wb = (unsigned short*)((char*)d_ws + WB_OFF);
    unsigned* scnt = (unsigned*)((char*)d_ws + SCNT_OFF);
    unsigned* bkt = (unsigned*)((char*)d_ws + BKT_OFF);

    hipMemsetAsync(scnt, 0, NBKT * SHARDS * sizeof(unsigned), stream);
    phase1<<<EBLK + CBLK, 256, 0, stream>>>(
        (const float4*)x, (uint2*)xb, (const float4*)W, (uint2*)wb,
        ei, scnt, bkt);
    agg_gemm<<<NBKT, 256, 0, stream>>>(xb, wb, scnt, bkt, b, out);
  } else if (ws_size >= WS_NEED_B) {
    unsigned* cnt = (unsigned*)((char*)d_ws + CNT_OFF);
    unsigned* off = (unsigned*)((char*)d_ws + OFF_OFF);
    unsigned* cur = (unsigned*)((char*)d_ws + CUR_OFF);
    int* csr = (int*)((char*)d_ws + CSR_OFF);
    float* Wt = (float*)((char*)d_ws + WT_OFF);
    unsigned* partial = (unsigned*)((char*)d_ws + PART_OFF);
    unsigned* base = (unsigned*)((char*)d_ws + BASE_OFF);

    hipMemsetAsync(cnt, 0, N_NODES * sizeof(unsigned), stream);
    transpose_w<<<(D * D + 255) / 256, 256, 0, stream>>>(W, Wt);
    count_kernel<<<(N_EDGES + 255) / 256, 256, 0, stream>>>(ei, cnt);
    scan_p1<<<SCAN_NBLK, 256, 0, stream>>>(cnt, partial);
    scan_p2<<<1, 256, 0, stream>>>(partial, base, off);
    scan_p3<<<SCAN_NBLK, 256, 0, stream>>>(cnt, base, off, cur);
    fill_kernel<<<(N_EDGES + 255) / 256, 256, 0, stream>>>(ei, cur, csr);
    aggregate_kernel<<<(N_NODES * 64 + 255) / 256, 256, 0, stream>>>(
        x, off, csr, out);
    gemm_relu_kernel<<<(N_NODES + 31) / 32, 256, 0, stream>>>(
        out, nullptr, Wt, b);
  } else {
    float* deg = (float*)d_ws;
    float* Wt = (float*)((char*)d_ws + 256 * 1024);
    hipMemsetAsync(d_out, 0, (size_t)N_NODES * D * sizeof(float), stream);
    hipMemsetAsync(deg, 0, N_NODES * sizeof(float), stream);
    transpose_w<<<(D * D + 255) / 256, 256, 0, stream>>>(W, Wt);
    scatter_kernel<<<(N_EDGES * 32) / 256, 256, 0, stream>>>(x, ei, out, deg);
    gemm_relu_kernel<<<(N_NODES + 31) / 32, 256, 0, stream>>>(out, deg, Wt, b);
  }
}

// Round 8
// 76.365 us; speedup vs baseline: 18.8268x; 1.2969x over previous
//
#include <hip/hip_runtime.h>

#define N_NODES 50000
#define N_EDGES 800000
#define D 128

// ---- Tier A: LDS-sorted coarse binning + fused agg+MFMA-gemm ----
#define NCRS 196        // coarse buckets: dst>>8 (256 nodes each)
#define CCAP 4608       // entries per coarse bucket; mean 4082, sigma 64
#define EPB 2048        // edges per bin block
#define NEBLK ((N_EDGES + EPB - 1) / EPB)   // 391
#define NBKT 1563       // fine buckets of 32 dst nodes (agg blocks)
#define LCAP 1536       // per-fine-bucket edge list; mean 512, sigma 23
#define XN (N_NODES * D / 4)   // float4 items of x
#define WN (D * D / 4)         // float4 items of W
#define CBLK ((XN + WN + 255) / 256)

// workspace layout, tier A (bytes)
#define XB_OFF   0u           // bf16[N_NODES*D]        12.8 MB
#define WB_OFF   12800000u    // bf16[D*D]              32 KB
#define GCUR_OFF 12832768u    // u32[NCRS] (pad 1 KB)
#define CRS_OFF  12833792u    // u32[NCRS*CCAP]         3.61 MB
#define WS_NEED_A (CRS_OFF + (unsigned)NCRS * CCAP * 4u)  // 16,446,464

// workspace layout, tier B (CSR path)
#define CNT_OFF 0u
#define OFF_OFF 200704u
#define CUR_OFF 401920u
#define CSR_OFF 602112u
#define WT_OFF  3802112u
#define PART_OFF 3867648u
#define BASE_OFF 3868672u
#define WS_NEED_B (BASE_OFF + 1024u)

#define SCAN_B 256
#define SCAN_NBLK ((N_NODES + SCAN_B - 1) / SCAN_B)  // 196

using bf16x8 = __attribute__((ext_vector_type(8))) short;
using f32x4 = __attribute__((ext_vector_type(4))) float;

// round-to-nearest-even f32->bf16
static __device__ __forceinline__ unsigned short bf16_rne(float f) {
  unsigned u = __float_as_uint(f);
  return (unsigned short)((u + 0x7fffu + ((u >> 16) & 1u)) >> 16);
}
static __device__ __forceinline__ unsigned pack_bf16(float a, float b) {
  return (unsigned)bf16_rne(a) | ((unsigned)bf16_rne(b) << 16);
}
static __device__ __forceinline__ float bf_lo(unsigned v) {
  return __uint_as_float(v << 16);
}
static __device__ __forceinline__ float bf_hi(unsigned v) {
  return __uint_as_float(v & 0xffff0000u);
}

// ===========================================================================
// phase1: blocks [0,NEBLK) LDS-sort 2048 edges by coarse bucket and bulk-
// flush sorted runs (1 global atomic per block-bucket, coalesced writes).
// Entry = (dst>>8)<<24 | src<<8 | (dst&255).  Blocks [NEBLK,..) convert
// x,W f32->bf16 (BW-bound, co-resident to keep CUs fed).
// ===========================================================================
__global__ __launch_bounds__(256) void phase1(
    const float4* __restrict__ x4, uint2* __restrict__ xb,
    const float4* __restrict__ w4, uint2* __restrict__ wb,
    const int* __restrict__ ei, unsigned* __restrict__ gcur,
    unsigned* __restrict__ crs) {
  __shared__ unsigned ent[EPB];   // 8 KB
  __shared__ unsigned srt[EPB];   // 8 KB
  __shared__ unsigned s[256];
  __shared__ unsigned offx[NCRS], cur[NCRS], gb[NCRS];
  const int t = threadIdx.x;

  if (blockIdx.x < NEBLK) {
    const int base = blockIdx.x * EPB;
    const int n = (N_EDGES - base < EPB) ? (N_EDGES - base) : EPB;
    for (int i = t; i < n; i += 256) {
      unsigned dst = (unsigned)ei[base + i];
      unsigned src = (unsigned)ei[N_EDGES + base + i];
      ent[i] = ((dst >> 8) << 24) | (src << 8) | (dst & 255u);
    }
    s[t] = 0;  // use s as the counter array first
    __syncthreads();
    for (int i = t; i < n; i += 256) atomicAdd(&s[ent[i] >> 24], 1u);
    __syncthreads();
    unsigned c = s[t];
    __syncthreads();
    s[t] = c;
    __syncthreads();
    #pragma unroll
    for (int o = 1; o < 256; o <<= 1) {
      unsigned a = (t >= o) ? s[t - o] : 0u;
      __syncthreads();
      s[t] += a;
      __syncthreads();
    }
    unsigned ex = s[t] - c;
    if (t < NCRS) {
      offx[t] = ex;
      cur[t] = ex;
      if (c) gb[t] = atomicAdd(&gcur[t], c);  // one atomic per block-bucket
    }
    __syncthreads();
    for (int i = t; i < n; i += 256) {
      unsigned e = ent[i];
      unsigned pos = atomicAdd(&cur[e >> 24], 1u);
      srt[pos] = e;
    }
    __syncthreads();
    // flush: consecutive i within a bucket -> consecutive global words
    for (int i = t; i < n; i += 256) {
      unsigned e = srt[i];
      unsigned k = e >> 24;
      unsigned idx = gb[k] + ((unsigned)i - offx[k]);
      if (idx < CCAP) crs[k * CCAP + idx] = e;
    }
  } else {
    int i = (blockIdx.x - NEBLK) * 256 + t;
    if (i < XN) {
      float4 v = x4[i];
      uint2 r;
      r.x = pack_bf16(v.x, v.y);
      r.y = pack_bf16(v.z, v.w);
      xb[i] = r;
    } else if (i < XN + WN) {
      int j = i - XN;
      float4 v = w4[j];
      uint2 r;
      r.x = pack_bf16(v.x, v.y);
      r.y = pack_bf16(v.z, v.w);
      wb[j] = r;
    }
  }
}

// ===========================================================================
// agg_gemm: one block per 32-node fine bucket (fb). coarse = fb>>3, sub=fb&7.
//  A) filter + counting sort of the coarse region (L2-hot: 8 blocks share
//     each region) -> per-node u16 src lists in LDS.
//  B) gather: 8 streams (wave-half), lane half p holds features 4p..4p+3 as
//     uint2; mean row -> packed bf16 in swizzled LDS abuf.
//  C) 32x128 @ 128x128 bf16 MFMA + bias + relu -> d_out (written once).
// ===========================================================================
__global__ __launch_bounds__(256) void agg_gemm(
    const unsigned* __restrict__ xb, const unsigned short* __restrict__ wb,
    const unsigned* __restrict__ gcur, const unsigned* __restrict__ crs,
    const float* __restrict__ b, float* __restrict__ out) {
  __shared__ unsigned short lst[LCAP];  // 3 KB
  __shared__ unsigned abuf[32 * 64];    // 8 KB packed-bf16 rows
  __shared__ unsigned cnt[32], off[32], cur[32];
  const int t = threadIdx.x;
  const int fb = blockIdx.x;
  const int coarse = fb >> 3;
  const unsigned sub = (unsigned)(fb & 7);

  unsigned n = gcur[coarse];
  n = (n > CCAP) ? CCAP : n;
  const unsigned* p = &crs[(unsigned)coarse * CCAP];

  if (t < 32) cnt[t] = 0;
  __syncthreads();
  for (unsigned i = t; i < n; i += 256) {
    unsigned e = p[i];
    if (((e >> 5) & 7u) == sub) atomicAdd(&cnt[e & 31u], 1u);
  }
  __syncthreads();
  if (t < 32) {
    unsigned c = cnt[t], x = c;
    #pragma unroll
    for (int o = 1; o < 32; o <<= 1) {
      unsigned v = __shfl_up(x, o, 64);
      if (t >= o) x += v;
    }
    off[t] = x - c;
    cur[t] = x - c;
  }
  __syncthreads();
  for (unsigned i = t; i < n; i += 256) {
    unsigned e = p[i];
    if (((e >> 5) & 7u) == sub) {
      unsigned pos = atomicAdd(&cur[e & 31u], 1u);
      if (pos < LCAP) lst[pos] = (unsigned short)((e >> 8) & 0xFFFFu);
    }
  }
  __syncthreads();

  // B) gather: stream = t>>5 (0..7); lane p2 = t&31 holds uint2 (4 feats)
  const int stream = t >> 5;
  const int p2 = t & 31;
  const uint2* x2 = (const uint2*)xb;
  for (int r = stream; r < 32; r += 8) {
    unsigned beg = off[r], c = cnt[r];
    float a0 = 0.f, a1 = 0.f, a2 = 0.f, a3 = 0.f;
    unsigned j = 0;
    for (; j + 4 <= c; j += 4) {
      unsigned s0 = lst[beg + j], s1 = lst[beg + j + 1];
      unsigned s2 = lst[beg + j + 2], s3 = lst[beg + j + 3];
      uint2 v0 = x2[(size_t)s0 * 32 + p2];
      uint2 v1 = x2[(size_t)s1 * 32 + p2];
      uint2 v2 = x2[(size_t)s2 * 32 + p2];
      uint2 v3 = x2[(size_t)s3 * 32 + p2];
      a0 += bf_lo(v0.x) + bf_lo(v1.x) + bf_lo(v2.x) + bf_lo(v3.x);
      a1 += bf_hi(v0.x) + bf_hi(v1.x) + bf_hi(v2.x) + bf_hi(v3.x);
      a2 += bf_lo(v0.y) + bf_lo(v1.y) + bf_lo(v2.y) + bf_lo(v3.y);
      a3 += bf_hi(v0.y) + bf_hi(v1.y) + bf_hi(v2.y) + bf_hi(v3.y);
    }
    for (; j < c; ++j) {
      uint2 v = x2[(size_t)lst[beg + j] * 32 + p2];
      a0 += bf_lo(v.x);
      a1 += bf_hi(v.x);
      a2 += bf_lo(v.y);
      a3 += bf_hi(v.y);
    }
    float inv = 1.0f / fmaxf((float)c, 1.0f);
    // swizzle: word w -> w ^ ((r&7)<<2); bit0 untouched -> uint2-aligned
    unsigned w0 = (unsigned)(2 * p2) ^ ((unsigned)(r & 7) << 2);
    *(uint2*)&abuf[r * 64 + w0] =
        make_uint2(pack_bf16(a0 * inv, a1 * inv), pack_bf16(a2 * inv, a3 * inv));
  }
  __syncthreads();

  // C) MFMA gemm: wave w -> rows [16*(w>>1),+16), cols [(w&1)*64,+64)
  const int wave = t >> 6, lane = t & 63;
  const int rt = wave >> 1;
  const int ch = (wave & 1) * 64;
  const int arow = lane & 15, khi = lane >> 4;
  const int ar = rt * 16 + arow;
  bf16x8 afrag[4];
  #pragma unroll
  for (int kb = 0; kb < 4; ++kb) {
    int w0 = (kb * 16 + khi * 4) ^ ((ar & 7) << 2);  // 4-word aligned group
    afrag[kb] = *(const bf16x8*)&abuf[ar * 64 + w0];
  }
  #pragma unroll
  for (int ct = 0; ct < 4; ++ct) {
    int o = ch + ct * 16 + arow;  // B row = W row = output feature
    f32x4 acc = (f32x4){0.f, 0.f, 0.f, 0.f};
    #pragma unroll
    for (int kb = 0; kb < 4; ++kb) {
      bf16x8 bfrag = *(const bf16x8*)(wb + o * 128 + kb * 32 + khi * 8);
      acc = __builtin_amdgcn_mfma_f32_16x16x32_bf16(afrag[kb], bfrag, acc,
                                                    0, 0, 0);
    }
    float bias = b[o];
    #pragma unroll
    for (int rg = 0; rg < 4; ++rg) {
      int row = fb * 32 + rt * 16 + khi * 4 + rg;
      if (row < N_NODES)
        out[(size_t)row * 128 + o] = fmaxf(acc[rg] + bias, 0.0f);
    }
  }
}

// ===========================================================================
// Tier B: CSR build + f32 aggregate + vector gemm
// ===========================================================================
__global__ __launch_bounds__(256) void transpose_w(
    const float* __restrict__ W, float* __restrict__ Wt) {
  int i = blockIdx.x * 256 + threadIdx.x;
  if (i < D * D) {
    int o = i >> 7, d = i & 127;
    Wt[d * D + o] = W[i];
  }
}

__global__ __launch_bounds__(256) void count_kernel(
    const int* __restrict__ ei, unsigned* __restrict__ cnt) {
  int e = blockIdx.x * 256 + threadIdx.x;
  if (e < N_EDGES) atomicAdd(&cnt[ei[e]], 1u);
}

__global__ __launch_bounds__(256) void scan_p1(
    const unsigned* __restrict__ cnt, unsigned* __restrict__ partial) {
  int t = threadIdx.x;
  int g = blockIdx.x * SCAN_B + t;
  unsigned c = (g < N_NODES) ? cnt[g] : 0u;
  #pragma unroll
  for (int o = 32; o > 0; o >>= 1) c += __shfl_down(c, o, 64);
  __shared__ unsigned ws[4];
  if ((t & 63) == 0) ws[t >> 6] = c;
  __syncthreads();
  if (t == 0) partial[blockIdx.x] = ws[0] + ws[1] + ws[2] + ws[3];
}

__global__ __launch_bounds__(256) void scan_p2(
    const unsigned* __restrict__ partial, unsigned* __restrict__ base,
    unsigned* __restrict__ off) {
  __shared__ unsigned s[256];
  int t = threadIdx.x;
  unsigned v = (t < SCAN_NBLK) ? partial[t] : 0u;
  s[t] = v;
  __syncthreads();
  #pragma unroll
  for (int o = 1; o < 256; o <<= 1) {
    unsigned a = (t >= o) ? s[t - o] : 0u;
    __syncthreads();
    s[t] += a;
    __syncthreads();
  }
  if (t < SCAN_NBLK) base[t] = s[t] - v;
  if (t == 255) off[N_NODES] = s[255];
}

__global__ __launch_bounds__(256) void scan_p3(
    const unsigned* __restrict__ cnt, const unsigned* __restrict__ base,
    unsigned* __restrict__ off, unsigned* __restrict__ cur) {
  __shared__ unsigned s[256];
  int t = threadIdx.x;
  int g = blockIdx.x * SCAN_B + t;
  unsigned c = (g < N_NODES) ? cnt[g] : 0u;
  s[t] = c;
  __syncthreads();
  #pragma unroll
  for (int o = 1; o < 256; o <<= 1) {
    unsigned a = (t >= o) ? s[t - o] : 0u;
    __syncthreads();
    s[t] += a;
    __syncthreads();
  }
  if (g < N_NODES) {
    unsigned e = base[blockIdx.x] + s[t] - c;
    off[g] = e;
    cur[g] = e;
  }
}

__global__ __launch_bounds__(256) void fill_kernel(
    const int* __restrict__ ei, unsigned* __restrict__ cur,
    int* __restrict__ csr) {
  int e = blockIdx.x * 256 + threadIdx.x;
  if (e < N_EDGES) {
    int dst = ei[e];
    int src = ei[N_EDGES + e];
    unsigned pos = atomicAdd(&cur[dst], 1u);
    csr[pos] = src;
  }
}

__global__ __launch_bounds__(256) void aggregate_kernel(
    const float* __restrict__ x, const unsigned* __restrict__ off,
    const int* __restrict__ csr, float* __restrict__ agg) {
  int wave = (blockIdx.x * 256 + threadIdx.x) >> 6;
  int lane = threadIdx.x & 63;
  if (wave >= N_NODES) return;
  unsigned beg = off[wave], end = off[wave + 1];
  const float2* x2 = (const float2*)x;
  float ax = 0.f, ay = 0.f;
  unsigned i = beg;
  for (; i + 2 <= end; i += 2) {
    int s0 = csr[i], s1 = csr[i + 1];
    float2 v0 = x2[(size_t)s0 * 64 + lane];
    float2 v1 = x2[(size_t)s1 * 64 + lane];
    ax += v0.x + v1.x;
    ay += v0.y + v1.y;
  }
  if (i < end) {
    float2 v = x2[(size_t)csr[i] * 64 + lane];
    ax += v.x;
    ay += v.y;
  }
  float inv = 1.0f / fmaxf((float)(end - beg), 1.0f);
  float2 r;
  r.x = ax * inv;
  r.y = ay * inv;
  ((float2*)agg)[(size_t)wave * 64 + lane] = r;
}

__global__ __launch_bounds__(256) void gemm_relu_kernel(
    float* __restrict__ io, const float* __restrict__ deg,
    const float* __restrict__ Wt, const float* __restrict__ b) {
  __shared__ float a_lds[32 * 128];
  int tid = threadIdx.x;
  int row0 = blockIdx.x * 32;
  const float4* g4 = (const float4*)io + (size_t)row0 * 32;
  #pragma unroll
  for (int k = 0; k < 4; ++k) {
    int f = k * 256 + tid;
    int r = f >> 5;
    int grow = row0 + r;
    float4 v = make_float4(0.f, 0.f, 0.f, 0.f);
    float inv = 1.0f;
    if (grow < N_NODES) {
      v = g4[f];
      if (deg) inv = 1.0f / fmaxf(deg[grow], 1.0f);
    }
    float* dstp = &a_lds[f * 4];
    dstp[0] = v.x * inv;
    dstp[1] = v.y * inv;
    dstp[2] = v.z * inv;
    dstp[3] = v.w * inv;
  }
  __syncthreads();
  int cq = tid & 31;
  int rb = (tid >> 5) * 4;
  float acc[4][4] = {};
  const float4* Wt4 = (const float4*)Wt;
  #pragma unroll 4
  for (int d = 0; d < 128; ++d) {
    float4 w = Wt4[d * 32 + cq];
    #pragma unroll
    for (int i = 0; i < 4; ++i) {
      float a = a_lds[(rb + i) * 128 + d];
      acc[i][0] += a * w.x;
      acc[i][1] += a * w.y;
      acc[i][2] += a * w.z;
      acc[i][3] += a * w.w;
    }
  }
  float4 bb = ((const float4*)b)[cq];
  float4* out4 = (float4*)io;
  #pragma unroll
  for (int i = 0; i < 4; ++i) {
    int grow = row0 + rb + i;
    if (grow < N_NODES) {
      float4 r;
      r.x = fmaxf(acc[i][0] + bb.x, 0.0f);
      r.y = fmaxf(acc[i][1] + bb.y, 0.0f);
      r.z = fmaxf(acc[i][2] + bb.z, 0.0f);
      r.w = fmaxf(acc[i][3] + bb.w, 0.0f);
      out4[(size_t)grow * 32 + cq] = r;
    }
  }
}

__global__ __launch_bounds__(256) void scatter_kernel(
    const float* __restrict__ x, const int* __restrict__ ei,
    float* __restrict__ agg, float* __restrict__ deg) {
  int gid = blockIdx.x * 256 + threadIdx.x;
  int e = gid >> 5;
  if (e >= N_EDGES) return;
  int part = gid & 31;
  int dst = ei[e];
  int src = ei[N_EDGES + e];
  const float4* x4 = (const float4*)x;
  float4 v = x4[(size_t)src * 32 + part];
  float* base = agg + (size_t)dst * D + part * 4;
  atomicAdd(base + 0, v.x);
  atomicAdd(base + 1, v.y);
  atomicAdd(base + 2, v.z);
  atomicAdd(base + 3, v.w);
  if (part == 0) atomicAdd(deg + dst, 1.0f);
}

extern "C" void kernel_launch(void* const* d_in, const int* in_sizes, int n_in,
                              void* d_out, int out_size, void* d_ws, size_t ws_size,
                              hipStream_t stream) {
  const float* x = (const float*)d_in[0];
  const int* ei = (const int*)d_in[1];
  const float* W = (const float*)d_in[2];
  const float* b = (const float*)d_in[3];
  float* out = (float*)d_out;

  if (ws_size >= WS_NEED_A) {
    unsigned* xb = (unsigned*)((char*)d_ws + XB_OFF);
    unsigned short* wb = (unsigned short*)((char*)d_ws + WB_OFF);
    unsigned* gcur = (unsigned*)((char*)d_ws + GCUR_OFF);
    unsigned* crs = (unsigned*)((char*)d_ws + CRS_OFF);

    hipMemsetAsync(gcur, 0, 1024, stream);
    phase1<<<NEBLK + CBLK, 256, 0, stream>>>(
        (const float4*)x, (uint2*)xb, (const float4*)W, (uint2*)wb,
        ei, gcur, crs);
    agg_gemm<<<NBKT, 256, 0, stream>>>(xb, wb, gcur, crs, b, out);
  } else if (ws_size >= WS_NEED_B) {
    unsigned* cnt = (unsigned*)((char*)d_ws + CNT_OFF);
    unsigned* off = (unsigned*)((char*)d_ws + OFF_OFF);
    unsigned* cur = (unsigned*)((char*)d_ws + CUR_OFF);
    int* csr = (int*)((char*)d_ws + CSR_OFF);
    float* Wt = (float*)((char*)d_ws + WT_OFF);
    unsigned* partial = (unsigned*)((char*)d_ws + PART_OFF);
    unsigned* base = (unsigned*)((char*)d_ws + BASE_OFF);

    hipMemsetAsync(cnt, 0, N_NODES * sizeof(unsigned), stream);
    transpose_w<<<(D * D + 255) / 256, 256, 0, stream>>>(W, Wt);
    count_kernel<<<(N_EDGES + 255) / 256, 256, 0, stream>>>(ei, cnt);
    scan_p1<<<SCAN_NBLK, 256, 0, stream>>>(cnt, partial);
    scan_p2<<<1, 256, 0, stream>>>(partial, base, off);
    scan_p3<<<SCAN_NBLK, 256, 0, stream>>>(cnt, base, off, cur);
    fill_kernel<<<(N_EDGES + 255) / 256, 256, 0, stream>>>(ei, cur, csr);
    aggregate_kernel<<<(N_NODES * 64 + 255) / 256, 256, 0, stream>>>(
        x, off, csr, out);
    gemm_relu_kernel<<<(N_NODES + 31) / 32, 256, 0, stream>>>(
        out, nullptr, Wt, b);
  } else {
    float* deg = (float*)d_ws;
    float* Wt = (float*)((char*)d_ws + 256 * 1024);
    hipMemsetAsync(d_out, 0, (size_t)N_NODES * D * sizeof(float), stream);
    hipMemsetAsync(deg, 0, N_NODES * sizeof(float), stream);
    transpose_w<<<(D * D + 255) / 256, 256, 0, stream>>>(W, Wt);
    scatter_kernel<<<(N_EDGES * 32) / 256, 256, 0, stream>>>(x, ei, out, deg);
    gemm_relu_kernel<<<(N_NODES + 31) / 32, 256, 0, stream>>>(out, deg, Wt, b);
  }
}